// Round 15
// baseline (283.200 us; speedup 1.0000x reference)
//
#include <hip/hip_runtime.h>

namespace {
constexpr int B_ = 64, S_ = 200, DV_ = 128, NC2_ = 4096;
constexpr int FCH = 8, NFCH = 25;    // fill: 25 chunks x 8 rows
}

typedef float f4v __attribute__((ext_vector_type(4)));
typedef float f32x4 __attribute__((ext_vector_type(4)));
typedef _Float16 half8 __attribute__((ext_vector_type(8)));
typedef _Float16 h2v __attribute__((ext_vector_type(2)));

#if defined(__has_builtin)
#if __has_builtin(__builtin_amdgcn_fdot2)
#define HAVE_FDOT2 1
#endif
#endif

__device__ __forceinline__ float dot2acc(h2v a, h2v b, float c) {
#ifdef HAVE_FDOT2
  return __builtin_amdgcn_fdot2(a, b, c, false);
#else
  return c + (float)a.x * (float)b.x + (float)a.y * (float)b.y;
#endif
}

// LDS-only barrier: no vmcnt drain.
__device__ __forceinline__ void lds_sync() {
  asm volatile("s_waitcnt lgkmcnt(0)\n\ts_barrier" ::: "memory");
}

// Full-wave (64) sum via DPP; result broadcast to all lanes via readlane 63.
__device__ __forceinline__ float wave_sum_bcast(float x) {
  float a = x;
  int s = __builtin_bit_cast(int, a);
  s = __builtin_amdgcn_update_dpp(0, s, 0x111, 0xf, 0xf, true);
  a += __builtin_bit_cast(float, s);
  s = __builtin_bit_cast(int, a);
  s = __builtin_amdgcn_update_dpp(0, s, 0x112, 0xf, 0xf, true);
  a += __builtin_bit_cast(float, s);
  s = __builtin_bit_cast(int, a);
  s = __builtin_amdgcn_update_dpp(0, s, 0x114, 0xf, 0xf, true);
  a += __builtin_bit_cast(float, s);
  s = __builtin_bit_cast(int, a);
  s = __builtin_amdgcn_update_dpp(0, s, 0x118, 0xf, 0xf, true);
  a += __builtin_bit_cast(float, s);
  s = __builtin_bit_cast(int, a);
  s = __builtin_amdgcn_update_dpp(0, s, 0x142, 0xf, 0xf, true);
  a += __builtin_bit_cast(float, s);
  s = __builtin_bit_cast(int, a);
  s = __builtin_amdgcn_update_dpp(0, s, 0x143, 0xf, 0xf, true);
  a += __builtin_bit_cast(float, s);
  s = __builtin_bit_cast(int, a);
  return __builtin_bit_cast(float, __builtin_amdgcn_readlane(s, 63));
}

// ---------------------------------------------------------------------------
// K_MAIN: blocks [0,64):    GRU per batch (broadcast-MFMA, LDS h-history,
//                           in-loop h store) + fused alpha. 512 threads.
//         blocks [64,1664): C2_seq fill with IN-BLOCK parallel scan prologue
//                           (thread-per-event, rounds = chain depth).
// ---------------------------------------------------------------------------
__global__ __launch_bounds__(512, 1) void k_main(
    const int* __restrict__ c2_seq, const int* __restrict__ d_seq,
    const int* __restrict__ r_seq, const float* __restrict__ D_emb,
    const float* __restrict__ v_d, const float* __restrict__ v_c2,
    const float* __restrict__ R_emb,
    const float* __restrict__ W_ih, const float* __restrict__ W_hh,
    const float* __restrict__ b_ih, const float* __restrict__ b_hh,
    const float* __restrict__ W1, const float* __restrict__ b1,
    const float* __restrict__ W2, const float* __restrict__ b2,
    const float* __restrict__ W3, const float* __restrict__ b3,
    const float* __restrict__ W4, const float* __restrict__ b4,
    float* __restrict__ out_alpha, float* __restrict__ out_h,
    float* __restrict__ out_c2)
{
  __shared__ __align__(16) char smem[(S_ + 1) * DV_ * 2 + 2 * S_ * 4 + 4 * 384 * 4];
  const int tid = threadIdx.x;

  if (blockIdx.x < B_) {
    // ------------------ GRU for batch b ------------------
    const int b = blockIdx.x;
    _Float16* hist = reinterpret_cast<_Float16*>(smem);          // (S_+1)*128 f16
    float* gl = reinterpret_cast<float*>(smem + (S_ + 1) * DV_ * 2);
    int* rl = reinterpret_cast<int*>(gl + S_);
    float* u_l = reinterpret_cast<float*>(rl + S_);              // [384] x4
    float* p0_l = u_l + 384;
    float* p1_l = p0_l + 384;
    float* bh_l = p1_l + 384;

    for (int i = tid; i < S_; i += 512) {
      gl[i] = D_emb[d_seq[b * S_ + i]];
      rl[i] = r_seq[b * S_ + i];
    }
    if (tid < DV_) hist[tid] = (_Float16)0.f;

    // collapsed input projections per gate row -> LDS
    if (tid < 384) {
      const int row = tid;
      const float4* wi =
          reinterpret_cast<const float4*>(W_ih + (size_t)row * 2 * DV_);
      const float4* vd4 = reinterpret_cast<const float4*>(v_d);
      const float4* re4 = reinterpret_cast<const float4*>(R_emb);
      float uu = 0.f, pp0 = 0.f, pp1 = 0.f;
#pragma unroll 8
      for (int k = 0; k < DV_ / 4; ++k) {
        float4 a = wi[k], vv = vd4[k];
        uu += a.x * vv.x + a.y * vv.y + a.z * vv.z + a.w * vv.w;
        float4 c = wi[DV_ / 4 + k];
        float4 r0 = re4[k], r1 = re4[DV_ / 4 + k];
        pp0 += c.x * r0.x + c.y * r0.y + c.z * r0.z + c.w * r0.w;
        pp1 += c.x * r1.x + c.y * r1.y + c.z * r1.z + c.w * r1.w;
      }
      const float bi = b_ih[row];
      u_l[row] = uu; p0_l[row] = pp0 + bi; p1_l[row] = pp1 + bi;
      bh_l[row] = b_hh[row];
    }

    // B-fragments (W_hh^T): lane l holds B[k=(l>>4)*8+j][col=l&15].
    const int w = tid >> 6, l = tid & 63;
    const int col = l & 15, kg = l >> 4;
    const int d = 16 * w + col;
    half8 bf[3][4];
#pragma unroll
    for (int g = 0; g < 3; ++g) {
      const float* wr = W_hh + (size_t)(g * DV_ + d) * DV_;
#pragma unroll
      for (int kt = 0; kt < 4; ++kt) {
        const int k0 = kt * 32 + kg * 8;
        const float4 lo = *reinterpret_cast<const float4*>(wr + k0);
        const float4 hi = *reinterpret_cast<const float4*>(wr + k0 + 4);
        half8 hb;
        hb[0] = (_Float16)lo.x; hb[1] = (_Float16)lo.y;
        hb[2] = (_Float16)lo.z; hb[3] = (_Float16)lo.w;
        hb[4] = (_Float16)hi.x; hb[5] = (_Float16)hi.y;
        hb[6] = (_Float16)hi.z; hb[7] = (_Float16)hi.w;
        bf[g][kt] = hb;
      }
    }
    __syncthreads();

    float u3[3], p03[3], p13[3], bh3[3];
#pragma unroll
    for (int g = 0; g < 3; ++g) {
      u3[g] = u_l[g * DV_ + d];
      p03[g] = p0_l[g * DV_ + d];
      p13[g] = p1_l[g * DV_ + d];
      bh3[g] = bh_l[g * DV_ + d];
    }
    float hprev = 0.f;
    float gv = gl[0];
    int rv = rl[0];

    float* outp = out_h + (size_t)b * S_ * DV_ + d;
    for (int t = 0; t < S_; ++t) {
      half8 af[4];
#pragma unroll
      for (int kt = 0; kt < 4; ++kt)
        af[kt] = *reinterpret_cast<const half8*>(&hist[t * DV_ + kt * 32 + kg * 8]);
      f32x4 a0 = {0.f, 0.f, 0.f, 0.f}, a1 = a0, a2 = a0;
#pragma unroll
      for (int kt = 0; kt < 4; ++kt) {
        a0 = __builtin_amdgcn_mfma_f32_16x16x32_f16(af[kt], bf[0][kt], a0, 0, 0, 0);
        a1 = __builtin_amdgcn_mfma_f32_16x16x32_f16(af[kt], bf[1][kt], a1, 0, 0, 0);
        a2 = __builtin_amdgcn_mfma_f32_16x16x32_f16(af[kt], bf[2][kt], a2, 0, 0, 0);
      }
      const float xr = gv * u3[0] + (rv ? p13[0] : p03[0]);
      const float xz = gv * u3[1] + (rv ? p13[1] : p03[1]);
      const float xn = gv * u3[2] + (rv ? p13[2] : p03[2]);
      const float r = 1.f / (1.f + __expf(-(xr + a0[0] + bh3[0])));
      const float z = 1.f / (1.f + __expf(-(xz + a1[0] + bh3[1])));
      const float nx = xn + r * (a2[0] + bh3[2]);
      const float e2 = __expf(2.f * nx);
      const float n = (e2 - 1.f) / (e2 + 1.f);
      const float hnew = (1.f - z) * n + z * hprev;
      hprev = hnew;
      if (kg == 0) {
        outp[(size_t)t * DV_] = hnew;                 // fire-and-forget f32
        hist[(t + 1) * DV_ + d] = (_Float16)hnew;
      }
      if (t + 1 < S_) { gv = gl[t + 1]; rv = rl[t + 1]; }
      lds_sync();
    }

    // ---------- fused alpha: 8 waves, rows s = wid + 8*i ----------
    const int lane = l;
    h2v w1L[64], w1H[64];
    {
      const float4* wrL = reinterpret_cast<const float4*>(W1 + (size_t)lane * DV_);
      const float4* wrH = reinterpret_cast<const float4*>(W1 + (size_t)(lane + 64) * DV_);
#pragma unroll
      for (int k = 0; k < 32; ++k) {
        float4 tL = wrL[k], tH = wrH[k];
        h2v a, bq;
        a.x = (_Float16)tL.x; a.y = (_Float16)tL.y;
        bq.x = (_Float16)tL.z; bq.y = (_Float16)tL.w;
        w1L[2 * k] = a; w1L[2 * k + 1] = bq;
        a.x = (_Float16)tH.x; a.y = (_Float16)tH.y;
        bq.x = (_Float16)tH.z; bq.y = (_Float16)tH.w;
        w1H[2 * k] = a; w1H[2 * k + 1] = bq;
      }
    }
    const float b1L = b1[lane], b1H = b1[lane + 64];
    const float w2L = W2[lane], w2H = W2[lane + 64];
    const float b2v = b2[0];
    for (int s = w; s < S_; s += 8) {
      const float4* hb = reinterpret_cast<const float4*>(hist + (s + 1) * DV_);
      float yL = 0.f, yH = 0.f;
#pragma unroll
      for (int k = 0; k < 16; ++k) {
        float4 hv = hb[k];
        h2v h0 = __builtin_bit_cast(h2v, hv.x);
        h2v h1 = __builtin_bit_cast(h2v, hv.y);
        h2v h2 = __builtin_bit_cast(h2v, hv.z);
        h2v h3 = __builtin_bit_cast(h2v, hv.w);
        yL = dot2acc(w1L[4 * k + 0], h0, yL);
        yH = dot2acc(w1H[4 * k + 0], h0, yH);
        yL = dot2acc(w1L[4 * k + 1], h1, yL);
        yH = dot2acc(w1H[4 * k + 1], h1, yH);
        yL = dot2acc(w1L[4 * k + 2], h2, yL);
        yH = dot2acc(w1H[4 * k + 2], h2, yH);
        yL = dot2acc(w1L[4 * k + 3], h3, yL);
        yH = dot2acc(w1H[4 * k + 3], h3, yH);
      }
      const float part = w2L * fmaxf(yL + b1L, 0.f) + w2H * fmaxf(yH + b1H, 0.f);
      const float sum = wave_sum_bcast(part);
      if (lane == 0) out_alpha[b * S_ + s] = sum + b2v;
    }
  } else {
    // ------------------ fill with in-block parallel scan ------------------
    const int blk = blockIdx.x - B_;
    const int b = blk / NFCH, c = blk % NFCH;
    const int s0 = c * FCH;
    float* a3s = reinterpret_cast<float*>(smem);            // [128] x5
    float* u3s = a3s + DV_;
    float* q0s = u3s + DV_;
    float* q1s = q0s + DV_;
    float* w4s = q1s + DV_;
    float* vals = w4s + DV_;                                // [200]
    float* gl = vals + S_;
    int* rl = reinterpret_cast<int*>(gl + S_);
    int* jl = rl + S_;
    int* prevs = jl + S_;
    int* done = prevs + S_;
    int* nresp = done + S_;

    if (tid == 0) *nresp = 0;
    for (int i = tid; i < S_; i += 512) {
      gl[i] = D_emb[d_seq[b * S_ + i]];
      rl[i] = r_seq[b * S_ + i];
      jl[i] = c2_seq[b * S_ + i];
      done[i] = 0;
    }
    if (tid < DV_) {
      const int d = tid;
      const float4* w3r = reinterpret_cast<const float4*>(W3 + (size_t)d * 3 * DV_);
      const float4* vc4 = reinterpret_cast<const float4*>(v_c2);
      const float4* vd4 = reinterpret_cast<const float4*>(v_d);
      const float4* re4 = reinterpret_cast<const float4*>(R_emb);
      float a3 = 0, u3 = 0, q0 = 0, q1 = 0;
#pragma unroll 8
      for (int k = 0; k < DV_ / 4; ++k) {
        float4 a = w3r[k], cc = vc4[k];
        a3 += a.x * cc.x + a.y * cc.y + a.z * cc.z + a.w * cc.w;
        float4 u = w3r[DV_ / 4 + k], dd = vd4[k];
        u3 += u.x * dd.x + u.y * dd.y + u.z * dd.z + u.w * dd.w;
        float4 cq = w3r[2 * (DV_ / 4) + k];
        float4 r0 = re4[k], r1 = re4[DV_ / 4 + k];
        q0 += cq.x * r0.x + cq.y * r0.y + cq.z * r0.z + cq.w * r0.w;
        q1 += cq.x * r1.x + cq.y * r1.y + cq.z * r1.z + cq.w * r1.w;
      }
      const float bb = b3[d];
      a3s[d] = a3; u3s[d] = u3; q0s[d] = q0 + bb; q1s[d] = q1 + bb;
      w4s[d] = W4[d];
    }
    __syncthreads();
    if (tid < S_) {
      const int jj = jl[tid];
      int p = -1;
      for (int q = tid - 1; q >= 0; --q)
        if (jl[q] == jj) { p = q; break; }
      prevs[tid] = p;
    }
    const float b4v = b4[0];
    __syncthreads();

    const int t = tid;  // one event per thread
    const float gv = (t < S_) ? gl[t] : 0.f;
    const int rv = (t < S_) ? rl[t] : 0;
    const int p = (t < S_) ? prevs[t] : -1;
    bool mine_done = (t >= S_);

    for (int round = 0; round < S_; ++round) {
      float myval = 0.f;
      bool computed = false;
      if (!mine_done && (p < 0 || done[p])) {
        const float beta = (p < 0) ? 0.f : vals[p];
        const float4* a34 = reinterpret_cast<const float4*>(a3s);
        const float4* u34 = reinterpret_cast<const float4*>(u3s);
        const float4* q04 = reinterpret_cast<const float4*>(q0s);
        const float4* q14 = reinterpret_cast<const float4*>(q1s);
        const float4* w44 = reinterpret_cast<const float4*>(w4s);
        float acc = 0.f;
#pragma unroll 8
        for (int k = 0; k < DV_ / 4; ++k) {
          float4 a = a34[k], u = u34[k];
          float4 q = rv ? q14[k] : q04[k];
          float4 ww = w44[k];
          float h0 = beta * a.x + gv * u.x + q.x;
          float h1 = beta * a.y + gv * u.y + q.y;
          float h2 = beta * a.z + gv * u.z + q.z;
          float h3 = beta * a.w + gv * u.w + q.w;
          acc += ww.x * fmaxf(h0, 0.f) + ww.y * fmaxf(h1, 0.f) +
                 ww.z * fmaxf(h2, 0.f) + ww.w * fmaxf(h3, 0.f);
        }
        myval = acc + b4v;
        computed = true;
      }
      __syncthreads();
      if (computed) {
        vals[t] = myval;
        done[t] = 1;
        mine_done = true;
        atomicAdd(nresp, 1);
      }
      __syncthreads();
      if (*nresp >= S_) break;
    }
    __syncthreads();

    // ------------------ streaming fill ------------------
    f4v v0 = {0.f, 0.f, 0.f, 0.f}, v1 = v0;

#define APPLY_EVT(T)                                                          \
    {                                                                         \
      const int j_ = jl[(T)];                                                 \
      const int f_ = j_ >> 2;                                                 \
      if ((f_ & 511) == tid) {                                                \
        const float vv_ = vals[(T)];                                          \
        const int rr_ = f_ >> 9, q_ = j_ & 3;                                 \
        if (rr_ == 0) {                                                       \
          if (q_ == 0) v0.x = vv_; else if (q_ == 1) v0.y = vv_;              \
          else if (q_ == 2) v0.z = vv_; else v0.w = vv_;                      \
        } else {                                                              \
          if (q_ == 0) v1.x = vv_; else if (q_ == 1) v1.y = vv_;              \
          else if (q_ == 2) v1.z = vv_; else v1.w = vv_;                      \
        }                                                                     \
      }                                                                       \
    }

    for (int tt = 0; tt < s0; ++tt) APPLY_EVT(tt);

    f4v* dst4 = reinterpret_cast<f4v*>(out_c2 + (size_t)b * S_ * NC2_);
    for (int s = s0; s < s0 + FCH; ++s) {
      APPLY_EVT(s);
      f4v* drow = dst4 + (size_t)s * (NC2_ / 4);
      __builtin_nontemporal_store(v0, drow + tid);
      __builtin_nontemporal_store(v1, drow + tid + 512);
    }
#undef APPLY_EVT
  }
}

extern "C" void kernel_launch(void* const* d_in, const int* in_sizes, int n_in,
                              void* d_out, int out_size, void* d_ws, size_t ws_size,
                              hipStream_t stream) {
  const int* c2_seq = (const int*)d_in[1];
  const int* d_seq = (const int*)d_in[3];
  const int* r_seq = (const int*)d_in[4];
  const float* D_emb = (const float*)d_in[5];
  const float* v_d = (const float*)d_in[6];
  const float* v_c2 = (const float*)d_in[7];
  const float* R_emb = (const float*)d_in[8];
  const float* W_ih = (const float*)d_in[9];
  const float* W_hh = (const float*)d_in[10];
  const float* b_ih = (const float*)d_in[11];
  const float* b_hh = (const float*)d_in[12];
  const float* W1 = (const float*)d_in[13];
  const float* b1 = (const float*)d_in[14];
  const float* W2 = (const float*)d_in[15];
  const float* b2 = (const float*)d_in[16];
  const float* W3 = (const float*)d_in[17];
  const float* b3 = (const float*)d_in[18];
  const float* W4 = (const float*)d_in[19];
  const float* b4 = (const float*)d_in[20];

  float* out = (float*)d_out;
  float* out_alpha = out;                                  // [B,S]
  float* out_h = out + B_ * S_;                            // [B,S,DV]
  float* out_c2 = out + B_ * S_ + (size_t)B_ * S_ * DV_;   // [B,S,NC2]

  k_main<<<dim3(B_ + B_ * NFCH), dim3(512), 0, stream>>>(
      c2_seq, d_seq, r_seq, D_emb, v_d, v_c2, R_emb, W_ih, W_hh, b_ih, b_hh,
      W1, b1, W2, b2, W3, b3, W4, b4, out_alpha, out_h, out_c2);
}

// Round 16
// 212.807 us; speedup vs baseline: 1.3308x; 1.3308x over previous
//
#include <hip/hip_runtime.h>

namespace {
constexpr int B_ = 64, S_ = 200, DV_ = 128, NC2_ = 4096;
constexpr int FCH = 4, NFCH = 50;    // fill: 50 chunks x 4 rows
constexpr int ACH = 50, NACH = 4;    // alpha: 4 chunks x 50 rows
}

typedef float f4v __attribute__((ext_vector_type(4)));
typedef float f32x4 __attribute__((ext_vector_type(4)));
typedef _Float16 half8 __attribute__((ext_vector_type(8)));

// LDS-only barrier: no vmcnt drain.
__device__ __forceinline__ void lds_sync() {
  asm volatile("s_waitcnt lgkmcnt(0)\n\ts_barrier" ::: "memory");
}

// Full-wave (64) sum via DPP; result broadcast to all lanes via readlane 63.
__device__ __forceinline__ float wave_sum_bcast(float x) {
  float a = x;
  int s = __builtin_bit_cast(int, a);
  s = __builtin_amdgcn_update_dpp(0, s, 0x111, 0xf, 0xf, true);
  a += __builtin_bit_cast(float, s);
  s = __builtin_bit_cast(int, a);
  s = __builtin_amdgcn_update_dpp(0, s, 0x112, 0xf, 0xf, true);
  a += __builtin_bit_cast(float, s);
  s = __builtin_bit_cast(int, a);
  s = __builtin_amdgcn_update_dpp(0, s, 0x114, 0xf, 0xf, true);
  a += __builtin_bit_cast(float, s);
  s = __builtin_bit_cast(int, a);
  s = __builtin_amdgcn_update_dpp(0, s, 0x118, 0xf, 0xf, true);
  a += __builtin_bit_cast(float, s);
  s = __builtin_bit_cast(int, a);
  s = __builtin_amdgcn_update_dpp(0, s, 0x142, 0xf, 0xf, true);
  a += __builtin_bit_cast(float, s);
  s = __builtin_bit_cast(int, a);
  s = __builtin_amdgcn_update_dpp(0, s, 0x143, 0xf, 0xf, true);
  a += __builtin_bit_cast(float, s);
  s = __builtin_bit_cast(int, a);
  return __builtin_bit_cast(float, __builtin_amdgcn_readlane(s, 63));
}

// ---------------------------------------------------------------------------
// K1: blocks [0,64):  GRU per batch via broadcast-MFMA. 4 waves; wave w owns
//                     dims [32w,32w+32) (2 N-tiles x 3 gates = 24 MFMA/step).
//                     h double-buffered f16[2][128]; one barrier/step.
//     blocks [64,128): C2 value scan per batch, single wave, DPP reduce.
// ---------------------------------------------------------------------------
__global__ __launch_bounds__(256, 1) void k1_gru_scan(
    const int* __restrict__ c2_seq, const int* __restrict__ d_seq,
    const int* __restrict__ r_seq, const float* __restrict__ D_emb,
    const float* __restrict__ v_d, const float* __restrict__ v_c2,
    const float* __restrict__ R_emb,
    const float* __restrict__ W_ih, const float* __restrict__ W_hh,
    const float* __restrict__ b_ih, const float* __restrict__ b_hh,
    const float* __restrict__ W3, const float* __restrict__ b3,
    const float* __restrict__ W4, const float* __restrict__ b4,
    float* __restrict__ out_h, float* __restrict__ vals_ws)
{
  __shared__ __align__(16) char smem[18944];
  const int tid = threadIdx.x;

  if (blockIdx.x < B_) {
    // ------------------ GRU for batch b ------------------
    const int b = blockIdx.x;
    _Float16* hist = reinterpret_cast<_Float16*>(smem);          // [2][128] f16
    float* gl = reinterpret_cast<float*>(smem + 512);            // [200]
    int* rl = reinterpret_cast<int*>(smem + 1312);               // [200]
    float* u_l = reinterpret_cast<float*>(smem + 2112);          // [384] x4
    float* p0_l = u_l + 384;
    float* p1_l = p0_l + 384;
    float* bh_l = p1_l + 384;

    for (int i = tid; i < S_; i += 256) {
      gl[i] = D_emb[d_seq[b * S_ + i]];
      rl[i] = r_seq[b * S_ + i];
    }
    if (tid < 256) reinterpret_cast<_Float16*>(hist)[tid] = (_Float16)0.f;

    // collapsed input projections per gate row -> LDS (rows 0..383)
    for (int row = tid; row < 384; row += 256) {
      const float4* wi =
          reinterpret_cast<const float4*>(W_ih + (size_t)row * 2 * DV_);
      const float4* vd4 = reinterpret_cast<const float4*>(v_d);
      const float4* re4 = reinterpret_cast<const float4*>(R_emb);
      float uu = 0.f, pp0 = 0.f, pp1 = 0.f;
#pragma unroll 8
      for (int k = 0; k < DV_ / 4; ++k) {
        float4 a = wi[k], vv = vd4[k];
        uu += a.x * vv.x + a.y * vv.y + a.z * vv.z + a.w * vv.w;
        float4 c = wi[DV_ / 4 + k];
        float4 r0 = re4[k], r1 = re4[DV_ / 4 + k];
        pp0 += c.x * r0.x + c.y * r0.y + c.z * r0.z + c.w * r0.w;
        pp1 += c.x * r1.x + c.y * r1.y + c.z * r1.z + c.w * r1.w;
      }
      const float bi = b_ih[row];
      u_l[row] = uu; p0_l[row] = pp0 + bi; p1_l[row] = pp1 + bi;
      bh_l[row] = b_hh[row];
    }

    // B-fragments (W_hh^T): lane l holds B[k=(l>>4)*8+j][col=l&15]
    // for gate g, tile j (dims 32w+16j+col), ktile kt.
    const int w = tid >> 6, l = tid & 63;
    const int col = l & 15, kg = l >> 4;
    const int d0 = 32 * w + col;     // tile 0 dim
    half8 bf[3][2][4];
#pragma unroll
    for (int g = 0; g < 3; ++g) {
#pragma unroll
      for (int j = 0; j < 2; ++j) {
        const float* wr = W_hh + (size_t)(g * DV_ + d0 + 16 * j) * DV_;
#pragma unroll
        for (int kt = 0; kt < 4; ++kt) {
          const int k0 = kt * 32 + kg * 8;
          const float4 lo = *reinterpret_cast<const float4*>(wr + k0);
          const float4 hi = *reinterpret_cast<const float4*>(wr + k0 + 4);
          half8 hb;
          hb[0] = (_Float16)lo.x; hb[1] = (_Float16)lo.y;
          hb[2] = (_Float16)lo.z; hb[3] = (_Float16)lo.w;
          hb[4] = (_Float16)hi.x; hb[5] = (_Float16)hi.y;
          hb[6] = (_Float16)hi.z; hb[7] = (_Float16)hi.w;
          bf[g][j][kt] = hb;
        }
      }
    }
    __syncthreads();

    // per-lane scalars for dims d0, d0+16 (3 gate rows each)
    float u3[3][2], p03[3][2], p13[3][2], bh3[3][2];
#pragma unroll
    for (int g = 0; g < 3; ++g)
#pragma unroll
      for (int j = 0; j < 2; ++j) {
        const int row = g * DV_ + d0 + 16 * j;
        u3[g][j] = u_l[row];
        p03[g][j] = p0_l[row];
        p13[g][j] = p1_l[row];
        bh3[g][j] = bh_l[row];
      }
    float hprev0 = 0.f, hprev1 = 0.f;
    float gv = gl[0];
    int rv = rl[0];

    float* outp = out_h + (size_t)b * S_ * DV_ + d0;
    for (int t = 0; t < S_; ++t) {
      const int cur = t & 1;
      half8 af[4];
#pragma unroll
      for (int kt = 0; kt < 4; ++kt)
        af[kt] = *reinterpret_cast<const half8*>(&hist[cur * DV_ + kt * 32 + kg * 8]);
      f32x4 ac[3][2];
#pragma unroll
      for (int g = 0; g < 3; ++g)
#pragma unroll
        for (int j = 0; j < 2; ++j) ac[g][j] = (f32x4){0.f, 0.f, 0.f, 0.f};
#pragma unroll
      for (int kt = 0; kt < 4; ++kt) {
        ac[0][0] = __builtin_amdgcn_mfma_f32_16x16x32_f16(af[kt], bf[0][0][kt], ac[0][0], 0, 0, 0);
        ac[1][0] = __builtin_amdgcn_mfma_f32_16x16x32_f16(af[kt], bf[1][0][kt], ac[1][0], 0, 0, 0);
        ac[2][0] = __builtin_amdgcn_mfma_f32_16x16x32_f16(af[kt], bf[2][0][kt], ac[2][0], 0, 0, 0);
        ac[0][1] = __builtin_amdgcn_mfma_f32_16x16x32_f16(af[kt], bf[0][1][kt], ac[0][1], 0, 0, 0);
        ac[1][1] = __builtin_amdgcn_mfma_f32_16x16x32_f16(af[kt], bf[1][1][kt], ac[1][1], 0, 0, 0);
        ac[2][1] = __builtin_amdgcn_mfma_f32_16x16x32_f16(af[kt], bf[2][1][kt], ac[2][1], 0, 0, 0);
      }
      // tile 0 activation (dim d0)
      {
        const float xr = gv * u3[0][0] + (rv ? p13[0][0] : p03[0][0]);
        const float xz = gv * u3[1][0] + (rv ? p13[1][0] : p03[1][0]);
        const float xn = gv * u3[2][0] + (rv ? p13[2][0] : p03[2][0]);
        const float r = 1.f / (1.f + __expf(-(xr + ac[0][0][0] + bh3[0][0])));
        const float z = 1.f / (1.f + __expf(-(xz + ac[1][0][0] + bh3[1][0])));
        const float nx = xn + r * (ac[2][0][0] + bh3[2][0]);
        const float e2 = __expf(2.f * nx);
        const float n = (e2 - 1.f) / (e2 + 1.f);
        hprev0 = (1.f - z) * n + z * hprev0;
      }
      // tile 1 activation (dim d0+16)
      {
        const float xr = gv * u3[0][1] + (rv ? p13[0][1] : p03[0][1]);
        const float xz = gv * u3[1][1] + (rv ? p13[1][1] : p03[1][1]);
        const float xn = gv * u3[2][1] + (rv ? p13[2][1] : p03[2][1]);
        const float r = 1.f / (1.f + __expf(-(xr + ac[0][1][0] + bh3[0][1])));
        const float z = 1.f / (1.f + __expf(-(xz + ac[1][1][0] + bh3[1][1])));
        const float nx = xn + r * (ac[2][1][0] + bh3[2][1]);
        const float e2 = __expf(2.f * nx);
        const float n = (e2 - 1.f) / (e2 + 1.f);
        hprev1 = (1.f - z) * n + z * hprev1;
      }
      if (kg == 0) {
        outp[(size_t)t * DV_] = hprev0;                      // fire-and-forget
        outp[(size_t)t * DV_ + 16] = hprev1;
        hist[(cur ^ 1) * DV_ + d0] = (_Float16)hprev0;
        hist[(cur ^ 1) * DV_ + d0 + 16] = (_Float16)hprev1;
      }
      if (t + 1 < S_) { gv = gl[t + 1]; rv = rl[t + 1]; }
      lds_sync();
    }
  } else {
    // ------------------ C2 value scan, single wave, DPP reduce ----------
    const int b = blockIdx.x - B_;
    float* C2s = reinterpret_cast<float*>(smem);             // 4096
    float* gl = reinterpret_cast<float*>(smem + 16384);      // [200]
    int* rl = reinterpret_cast<int*>(smem + 17184);
    int* jl = reinterpret_cast<int*>(smem + 17984);
    for (int i = tid; i < NC2_; i += 256) C2s[i] = 0.f;
    for (int i = tid; i < S_; i += 256) {
      gl[i] = D_emb[d_seq[b * S_ + i]];
      rl[i] = r_seq[b * S_ + i];
      jl[i] = c2_seq[b * S_ + i];
    }
    __syncthreads();
    if (tid >= 64) return;
    const int lane = tid;
    float a3L = 0, u3L = 0, q0L = 0, q1L = 0;
    float a3H = 0, u3H = 0, q0H = 0, q1H = 0;
    {
      const float4* vc4 = reinterpret_cast<const float4*>(v_c2);
      const float4* vd4 = reinterpret_cast<const float4*>(v_d);
      const float4* re4 = reinterpret_cast<const float4*>(R_emb);
      const float4* wL = reinterpret_cast<const float4*>(W3 + (size_t)lane * 3 * DV_);
      const float4* wH = reinterpret_cast<const float4*>(W3 + (size_t)(lane + 64) * 3 * DV_);
#pragma unroll 8
      for (int k = 0; k < DV_ / 4; ++k) {
        float4 cc = vc4[k], dd = vd4[k];
        float4 r0 = re4[k], r1 = re4[DV_ / 4 + k];
        float4 aL = wL[k], aH = wH[k];
        a3L += aL.x * cc.x + aL.y * cc.y + aL.z * cc.z + aL.w * cc.w;
        a3H += aH.x * cc.x + aH.y * cc.y + aH.z * cc.z + aH.w * cc.w;
        float4 bL = wL[DV_ / 4 + k], bH = wH[DV_ / 4 + k];
        u3L += bL.x * dd.x + bL.y * dd.y + bL.z * dd.z + bL.w * dd.w;
        u3H += bH.x * dd.x + bH.y * dd.y + bH.z * dd.z + bH.w * dd.w;
        float4 cL = wL[2 * (DV_ / 4) + k], cH = wH[2 * (DV_ / 4) + k];
        q0L += cL.x * r0.x + cL.y * r0.y + cL.z * r0.z + cL.w * r0.w;
        q1L += cL.x * r1.x + cL.y * r1.y + cL.z * r1.z + cL.w * r1.w;
        q0H += cH.x * r0.x + cH.y * r0.y + cH.z * r0.z + cH.w * r0.w;
        q1H += cH.x * r1.x + cH.y * r1.y + cH.z * r1.z + cH.w * r1.w;
      }
      float bbL = b3[lane], bbH = b3[lane + 64];
      q0L += bbL; q1L += bbL; q0H += bbH; q1H += bbH;
    }
    const float w4L = W4[lane], w4H = W4[lane + 64];
    const float b4v = b4[0];

    int jc = jl[0];
    float gv = gl[0];
    int rv = rl[0];
    float pf = 0.f;
    float lastv = 0.f;
    int lastj = -1;
    for (int t = 0; t < S_; ++t) {
      const int tn = (t + 1 < S_) ? t + 1 : 0;
      const int jn = jl[tn];
      const float gvn = gl[tn];
      const int rvn = rl[tn];
      const float pfn = C2s[jn];   // prefetch; patched via lastj/lastv
      const float beta = (jc == lastj) ? lastv : pf;
      float hL = beta * a3L + gv * u3L + (rv ? q1L : q0L);
      float hH = beta * a3H + gv * u3H + (rv ? q1H : q0H);
      const float part = fmaxf(hL, 0.f) * w4L + fmaxf(hH, 0.f) * w4H;
      const float val = wave_sum_bcast(part) + b4v;
      if (lane == 0) {
        C2s[jc] = val;
        vals_ws[b * S_ + t] = val;
      }
      lastj = jc; lastv = val;
      jc = jn; gv = gvn; rv = rvn; pf = pfn;
    }
  }
}

// ---------------------------------------------------------------------------
// K2: blocks [0,256):    alpha MLP, (b, 50-row chunk)
//     blocks [256,3456): C2_seq fill, (b, 4-row chunk), barrier-free rows
// ---------------------------------------------------------------------------
__global__ __launch_bounds__(256) void k2_alpha_fill(
    const int* __restrict__ c2_seq,
    const float* __restrict__ W1, const float* __restrict__ b1,
    const float* __restrict__ W2, const float* __restrict__ b2,
    const float* __restrict__ vals_ws, const float* __restrict__ h_seq,
    float* __restrict__ out_alpha, float* __restrict__ out_c2)
{
  const int tid = threadIdx.x;
  if (blockIdx.x < NACH * B_) {
    // ------------------ alpha ------------------
    const int b = blockIdx.x >> 2, c = blockIdx.x & 3;
    const int sbeg = c * ACH, send = sbeg + ACH;
    __shared__ float4 hb4[2][DV_ / 4];
    __shared__ float red[4];
    const int grp = tid >> 7, d = tid & 127;
    float w1r[DV_];
    {
      const float4* wr = reinterpret_cast<const float4*>(W1 + (size_t)d * DV_);
#pragma unroll
      for (int k = 0; k < DV_ / 4; ++k) {
        float4 t4 = wr[k];
        w1r[4 * k] = t4.x; w1r[4 * k + 1] = t4.y;
        w1r[4 * k + 2] = t4.z; w1r[4 * k + 3] = t4.w;
      }
    }
    const float b1v = b1[d], w2v = W2[d], b2v = b2[0];
    float* hb = reinterpret_cast<float*>(hb4[grp]);
    for (int s = sbeg; s < send; s += 2) {
      const int ss = s + grp;
      hb[d] = h_seq[((size_t)(b * S_ + ss)) * DV_ + d];
      __syncthreads();
      float y0 = b1v, y1 = 0, y2 = 0, y3 = 0;
#pragma unroll
      for (int k = 0; k < DV_ / 4; ++k) {
        float4 hv = hb4[grp][k];
        y0 += w1r[4 * k + 0] * hv.x; y1 += w1r[4 * k + 1] * hv.y;
        y2 += w1r[4 * k + 2] * hv.z; y3 += w1r[4 * k + 3] * hv.w;
      }
      float part = w2v * fmaxf((y0 + y1) + (y2 + y3), 0.f);
#pragma unroll
      for (int off = 1; off < 64; off <<= 1) part += __shfl_xor(part, off);
      if ((tid & 63) == 0) red[tid >> 6] = part;
      __syncthreads();
      if (d == 0) out_alpha[b * S_ + ss] = red[2 * grp] + red[2 * grp + 1] + b2v;
      __syncthreads();
    }
  } else {
    // ------------------ C2_seq fill ------------------
    const int blk = blockIdx.x - NACH * B_;
    const int b = blk / NFCH, c = blk % NFCH;
    const int s0 = c * FCH;
    __shared__ float vls[S_];
    __shared__ int jl[S_];
    for (int i = tid; i < S_; i += 256) {
      vls[i] = vals_ws[b * S_ + i];
      jl[i] = c2_seq[b * S_ + i];
    }
    __syncthreads();
    // thread owns 16 columns: float4 indices f = tid + jj*256
    f4v v0 = {0.f, 0.f, 0.f, 0.f}, v1 = v0, v2 = v0, v3 = v0;

#define APPLY_EVT(T)                                                          \
    {                                                                         \
      const int j_ = jl[(T)];                                                 \
      const int f_ = j_ >> 2;                                                 \
      if ((f_ & 255) == tid) {                                                \
        const float vv_ = vls[(T)];                                           \
        const int rr_ = f_ >> 8, q_ = j_ & 3;                                 \
        if (rr_ == 0) {                                                       \
          if (q_ == 0) v0.x = vv_; else if (q_ == 1) v0.y = vv_;              \
          else if (q_ == 2) v0.z = vv_; else v0.w = vv_;                      \
        } else if (rr_ == 1) {                                                \
          if (q_ == 0) v1.x = vv_; else if (q_ == 1) v1.y = vv_;              \
          else if (q_ == 2) v1.z = vv_; else v1.w = vv_;                      \
        } else if (rr_ == 2) {                                                \
          if (q_ == 0) v2.x = vv_; else if (q_ == 1) v2.y = vv_;              \
          else if (q_ == 2) v2.z = vv_; else v2.w = vv_;                      \
        } else {                                                              \
          if (q_ == 0) v3.x = vv_; else if (q_ == 1) v3.y = vv_;              \
          else if (q_ == 2) v3.z = vv_; else v3.w = vv_;                      \
        }                                                                     \
      }                                                                       \
    }

    for (int t = 0; t < s0; ++t) APPLY_EVT(t);

    f4v* dst4 = reinterpret_cast<f4v*>(out_c2 + (size_t)b * S_ * NC2_);
    for (int s = s0; s < s0 + FCH; ++s) {
      APPLY_EVT(s);
      f4v* drow = dst4 + (size_t)s * (NC2_ / 4);
      __builtin_nontemporal_store(v0, drow + tid);
      __builtin_nontemporal_store(v1, drow + tid + 256);
      __builtin_nontemporal_store(v2, drow + tid + 512);
      __builtin_nontemporal_store(v3, drow + tid + 768);
    }
#undef APPLY_EVT
  }
}

extern "C" void kernel_launch(void* const* d_in, const int* in_sizes, int n_in,
                              void* d_out, int out_size, void* d_ws, size_t ws_size,
                              hipStream_t stream) {
  const int* c2_seq = (const int*)d_in[1];
  const int* d_seq = (const int*)d_in[3];
  const int* r_seq = (const int*)d_in[4];
  const float* D_emb = (const float*)d_in[5];
  const float* v_d = (const float*)d_in[6];
  const float* v_c2 = (const float*)d_in[7];
  const float* R_emb = (const float*)d_in[8];
  const float* W_ih = (const float*)d_in[9];
  const float* W_hh = (const float*)d_in[10];
  const float* b_ih = (const float*)d_in[11];
  const float* b_hh = (const float*)d_in[12];
  const float* W1 = (const float*)d_in[13];
  const float* b1 = (const float*)d_in[14];
  const float* W2 = (const float*)d_in[15];
  const float* b2 = (const float*)d_in[16];
  const float* W3 = (const float*)d_in[17];
  const float* b3 = (const float*)d_in[18];
  const float* W4 = (const float*)d_in[19];
  const float* b4 = (const float*)d_in[20];

  float* out = (float*)d_out;
  float* out_alpha = out;                                  // [B,S]
  float* out_h = out + B_ * S_;                            // [B,S,DV]
  float* out_c2 = out + B_ * S_ + (size_t)B_ * S_ * DV_;   // [B,S,NC2]
  float* vals_ws = (float*)d_ws;                           // [B*S] floats

  k1_gru_scan<<<dim3(2 * B_), dim3(256), 0, stream>>>(
      c2_seq, d_seq, r_seq, D_emb, v_d, v_c2, R_emb, W_ih, W_hh, b_ih, b_hh,
      W3, b3, W4, b4, out_h, vals_ws);
  k2_alpha_fill<<<dim3(NACH * B_ + B_ * NFCH), dim3(256), 0, stream>>>(
      c2_seq, W1, b1, W2, b2, vals_ws, out_h, out_alpha, out_c2);
}

// Round 17
// 192.864 us; speedup vs baseline: 1.4684x; 1.1034x over previous
//
#include <hip/hip_runtime.h>

namespace {
constexpr int B_ = 64, S_ = 200, DV_ = 128, NC2_ = 4096;
constexpr int FCH = 8, NFCH = 25;    // fill: 25 chunks x 8 rows
}

typedef float f4v __attribute__((ext_vector_type(4)));
typedef float f32x4 __attribute__((ext_vector_type(4)));
typedef _Float16 half8 __attribute__((ext_vector_type(8)));

// LDS-only barrier: no vmcnt drain.
__device__ __forceinline__ void lds_sync() {
  asm volatile("s_waitcnt lgkmcnt(0)\n\ts_barrier" ::: "memory");
}

// ---------------------------------------------------------------------------
// K1: parallel C2 value scan — one THREAD per event; in-thread 128-dim dot
//     from LDS coefficient arrays; rounds = chain depth (two-phase, race-free).
//     (validated R14)
// ---------------------------------------------------------------------------
__global__ __launch_bounds__(256) void k_scan(
    const int* __restrict__ c2_seq, const int* __restrict__ d_seq,
    const int* __restrict__ r_seq, const float* __restrict__ D_emb,
    const float* __restrict__ v_d, const float* __restrict__ v_c2,
    const float* __restrict__ R_emb,
    const float* __restrict__ W3, const float* __restrict__ b3,
    const float* __restrict__ W4, const float* __restrict__ b4,
    float* __restrict__ vals_ws)
{
  __shared__ float a3s[DV_], u3s[DV_], q0s[DV_], q1s[DV_], w4s[DV_];
  __shared__ float vals[S_], gl[S_];
  __shared__ int rl[S_], jl[S_], prevs[S_], done[S_];
  __shared__ int nres;
  const int tid = threadIdx.x;
  const int b = blockIdx.x;

  if (tid == 0) nres = 0;
  for (int i = tid; i < S_; i += 256) {
    gl[i] = D_emb[d_seq[b * S_ + i]];
    rl[i] = r_seq[b * S_ + i];
    jl[i] = c2_seq[b * S_ + i];
    done[i] = 0;
  }
  if (tid < DV_) {
    const int d = tid;
    const float4* w3r = reinterpret_cast<const float4*>(W3 + (size_t)d * 3 * DV_);
    const float4* vc4 = reinterpret_cast<const float4*>(v_c2);
    const float4* vd4 = reinterpret_cast<const float4*>(v_d);
    const float4* re4 = reinterpret_cast<const float4*>(R_emb);
    float a3 = 0, u3 = 0, q0 = 0, q1 = 0;
#pragma unroll 8
    for (int k = 0; k < DV_ / 4; ++k) {
      float4 a = w3r[k], cc = vc4[k];
      a3 += a.x * cc.x + a.y * cc.y + a.z * cc.z + a.w * cc.w;
      float4 u = w3r[DV_ / 4 + k], dd = vd4[k];
      u3 += u.x * dd.x + u.y * dd.y + u.z * dd.z + u.w * dd.w;
      float4 c = w3r[2 * (DV_ / 4) + k];
      float4 r0 = re4[k], r1 = re4[DV_ / 4 + k];
      q0 += c.x * r0.x + c.y * r0.y + c.z * r0.z + c.w * r0.w;
      q1 += c.x * r1.x + c.y * r1.y + c.z * r1.z + c.w * r1.w;
    }
    const float bb = b3[d];
    a3s[d] = a3; u3s[d] = u3; q0s[d] = q0 + bb; q1s[d] = q1 + bb;
    w4s[d] = W4[d];
  }
  __syncthreads();
  if (tid < S_) {
    const int jj = jl[tid];
    int p = -1;
    for (int q = tid - 1; q >= 0; --q)
      if (jl[q] == jj) { p = q; break; }
    prevs[tid] = p;
  }
  const float b4v = b4[0];
  __syncthreads();

  const int t = tid;  // one event per thread (256 >= 200)
  const float gv = (t < S_) ? gl[t] : 0.f;
  const int rv = (t < S_) ? rl[t] : 0;
  const int p = (t < S_) ? prevs[t] : -1;
  bool mine_done = (t >= S_);

  for (int round = 0; round < S_; ++round) {
    float myval = 0.f;
    bool computed = false;
    if (!mine_done && (p < 0 || done[p])) {
      const float beta = (p < 0) ? 0.f : vals[p];
      const float4* a34 = reinterpret_cast<const float4*>(a3s);
      const float4* u34 = reinterpret_cast<const float4*>(u3s);
      const float4* q04 = reinterpret_cast<const float4*>(q0s);
      const float4* q14 = reinterpret_cast<const float4*>(q1s);
      const float4* w44 = reinterpret_cast<const float4*>(w4s);
      float acc = 0.f;
#pragma unroll 8
      for (int k = 0; k < DV_ / 4; ++k) {
        float4 a = a34[k], u = u34[k];
        float4 q = rv ? q14[k] : q04[k];
        float4 w = w44[k];
        float h0 = beta * a.x + gv * u.x + q.x;
        float h1 = beta * a.y + gv * u.y + q.y;
        float h2 = beta * a.z + gv * u.z + q.z;
        float h3 = beta * a.w + gv * u.w + q.w;
        acc += w.x * fmaxf(h0, 0.f) + w.y * fmaxf(h1, 0.f) +
               w.z * fmaxf(h2, 0.f) + w.w * fmaxf(h3, 0.f);
      }
      myval = acc + b4v;
      computed = true;
    }
    __syncthreads();
    if (computed) {
      vals[t] = myval;
      done[t] = 1;
      mine_done = true;
      atomicAdd(&nres, 1);
    }
    __syncthreads();
    if (nres >= S_) break;
  }
  for (int i = tid; i < S_; i += 256) vals_ws[b * S_ + i] = vals[i];
}

// ---------------------------------------------------------------------------
// K2: blocks [0,64):    GRU per batch via broadcast-MFMA (R12 structure,
//                       in-loop h store). 512 threads.
//     blocks [64,1664): C2_seq fill, (b, 8-row chunk), 512 threads.
// ---------------------------------------------------------------------------
__global__ __launch_bounds__(512, 1) void k2_gru_fill(
    const int* __restrict__ c2_seq, const int* __restrict__ d_seq,
    const int* __restrict__ r_seq, const float* __restrict__ D_emb,
    const float* __restrict__ v_d, const float* __restrict__ R_emb,
    const float* __restrict__ W_ih, const float* __restrict__ W_hh,
    const float* __restrict__ b_ih, const float* __restrict__ b_hh,
    const float* __restrict__ vals_ws,
    float* __restrict__ out_h, float* __restrict__ out_c2)
{
  __shared__ __align__(16) char smem[18944];
  const int tid = threadIdx.x;

  if (blockIdx.x < B_) {
    // ------------------ GRU for batch b ------------------
    const int b = blockIdx.x;
    _Float16* hist = reinterpret_cast<_Float16*>(smem);          // [2][128] f16
    float* gl = reinterpret_cast<float*>(smem + 512);            // [200]
    int* rl = reinterpret_cast<int*>(smem + 1312);               // [200]
    float* u_l = reinterpret_cast<float*>(smem + 2112);          // [384] x4
    float* p0_l = u_l + 384;
    float* p1_l = p0_l + 384;
    float* bh_l = p1_l + 384;

    for (int i = tid; i < S_; i += 512) {
      gl[i] = D_emb[d_seq[b * S_ + i]];
      rl[i] = r_seq[b * S_ + i];
    }
    if (tid < 256) reinterpret_cast<_Float16*>(hist)[tid] = (_Float16)0.f;

    // collapsed input projections per gate row -> LDS
    if (tid < 384) {
      const int row = tid;
      const float4* wi =
          reinterpret_cast<const float4*>(W_ih + (size_t)row * 2 * DV_);
      const float4* vd4 = reinterpret_cast<const float4*>(v_d);
      const float4* re4 = reinterpret_cast<const float4*>(R_emb);
      float uu = 0.f, pp0 = 0.f, pp1 = 0.f;
#pragma unroll 8
      for (int k = 0; k < DV_ / 4; ++k) {
        float4 a = wi[k], vv = vd4[k];
        uu += a.x * vv.x + a.y * vv.y + a.z * vv.z + a.w * vv.w;
        float4 c = wi[DV_ / 4 + k];
        float4 r0 = re4[k], r1 = re4[DV_ / 4 + k];
        pp0 += c.x * r0.x + c.y * r0.y + c.z * r0.z + c.w * r0.w;
        pp1 += c.x * r1.x + c.y * r1.y + c.z * r1.z + c.w * r1.w;
      }
      const float bi = b_ih[row];
      u_l[row] = uu; p0_l[row] = pp0 + bi; p1_l[row] = pp1 + bi;
      bh_l[row] = b_hh[row];
    }

    // B-fragments (W_hh^T): lane l holds B[k=(l>>4)*8+j][col=l&15].
    const int w = tid >> 6, l = tid & 63;
    const int col = l & 15, kg = l >> 4;
    const int d = 16 * w + col;
    half8 bf[3][4];
#pragma unroll
    for (int g = 0; g < 3; ++g) {
      const float* wr = W_hh + (size_t)(g * DV_ + d) * DV_;
#pragma unroll
      for (int kt = 0; kt < 4; ++kt) {
        const int k0 = kt * 32 + kg * 8;
        const float4 lo = *reinterpret_cast<const float4*>(wr + k0);
        const float4 hi = *reinterpret_cast<const float4*>(wr + k0 + 4);
        half8 hb;
        hb[0] = (_Float16)lo.x; hb[1] = (_Float16)lo.y;
        hb[2] = (_Float16)lo.z; hb[3] = (_Float16)lo.w;
        hb[4] = (_Float16)hi.x; hb[5] = (_Float16)hi.y;
        hb[6] = (_Float16)hi.z; hb[7] = (_Float16)hi.w;
        bf[g][kt] = hb;
      }
    }
    __syncthreads();

    float u3[3], p03[3], p13[3], bh3[3];
#pragma unroll
    for (int g = 0; g < 3; ++g) {
      u3[g] = u_l[g * DV_ + d];
      p03[g] = p0_l[g * DV_ + d];
      p13[g] = p1_l[g * DV_ + d];
      bh3[g] = bh_l[g * DV_ + d];
    }
    float hprev = 0.f;
    float gv = gl[0];
    int rv = rl[0];

    float* outp = out_h + (size_t)b * S_ * DV_ + d;
    for (int t = 0; t < S_; ++t) {
      const int cur = t & 1;
      half8 af[4];
#pragma unroll
      for (int kt = 0; kt < 4; ++kt)
        af[kt] = *reinterpret_cast<const half8*>(&hist[cur * DV_ + kt * 32 + kg * 8]);
      f32x4 a0 = {0.f, 0.f, 0.f, 0.f}, a1 = a0, a2 = a0;
#pragma unroll
      for (int kt = 0; kt < 4; ++kt) {
        a0 = __builtin_amdgcn_mfma_f32_16x16x32_f16(af[kt], bf[0][kt], a0, 0, 0, 0);
        a1 = __builtin_amdgcn_mfma_f32_16x16x32_f16(af[kt], bf[1][kt], a1, 0, 0, 0);
        a2 = __builtin_amdgcn_mfma_f32_16x16x32_f16(af[kt], bf[2][kt], a2, 0, 0, 0);
      }
      const float xr = gv * u3[0] + (rv ? p13[0] : p03[0]);
      const float xz = gv * u3[1] + (rv ? p13[1] : p03[1]);
      const float xn = gv * u3[2] + (rv ? p13[2] : p03[2]);
      const float r = 1.f / (1.f + __expf(-(xr + a0[0] + bh3[0])));
      const float z = 1.f / (1.f + __expf(-(xz + a1[0] + bh3[1])));
      const float nx = xn + r * (a2[0] + bh3[2]);
      const float e2 = __expf(2.f * nx);
      const float n = (e2 - 1.f) / (e2 + 1.f);
      const float hnew = (1.f - z) * n + z * hprev;
      hprev = hnew;
      if (kg == 0) {
        outp[(size_t)t * DV_] = hnew;                 // fire-and-forget f32
        hist[(cur ^ 1) * DV_ + d] = (_Float16)hnew;
      }
      if (t + 1 < S_) { gv = gl[t + 1]; rv = rl[t + 1]; }
      lds_sync();
    }
  } else {
    // ------------------ C2_seq fill (512 threads) ------------------
    const int blk = blockIdx.x - B_;
    const int b = blk / NFCH, c = blk % NFCH;
    const int s0 = c * FCH;
    float* vls = reinterpret_cast<float*>(smem);
    int* jl = reinterpret_cast<int*>(vls + S_);
    for (int i = tid; i < S_; i += 512) {
      vls[i] = vals_ws[b * S_ + i];
      jl[i] = c2_seq[b * S_ + i];
    }
    __syncthreads();
    // thread owns 8 columns: float4 indices f = tid + jj*512, jj=0..1
    f4v v0 = {0.f, 0.f, 0.f, 0.f}, v1 = v0;

#define APPLY_EVT(T)                                                          \
    {                                                                         \
      const int j_ = jl[(T)];                                                 \
      const int f_ = j_ >> 2;                                                 \
      if ((f_ & 511) == tid) {                                                \
        const float vv_ = vls[(T)];                                           \
        const int rr_ = f_ >> 9, q_ = j_ & 3;                                 \
        if (rr_ == 0) {                                                       \
          if (q_ == 0) v0.x = vv_; else if (q_ == 1) v0.y = vv_;              \
          else if (q_ == 2) v0.z = vv_; else v0.w = vv_;                      \
        } else {                                                              \
          if (q_ == 0) v1.x = vv_; else if (q_ == 1) v1.y = vv_;              \
          else if (q_ == 2) v1.z = vv_; else v1.w = vv_;                      \
        }                                                                     \
      }                                                                       \
    }

    for (int t = 0; t < s0; ++t) APPLY_EVT(t);

    f4v* dst4 = reinterpret_cast<f4v*>(out_c2 + (size_t)b * S_ * NC2_);
    for (int s = s0; s < s0 + FCH; ++s) {
      APPLY_EVT(s);
      f4v* drow = dst4 + (size_t)s * (NC2_ / 4);
      __builtin_nontemporal_store(v0, drow + tid);
      __builtin_nontemporal_store(v1, drow + tid + 512);
    }
#undef APPLY_EVT
  }
}

// ---------------------------------------------------------------------------
// K3: alpha MLP, (b, 50-row chunk), 256 blocks x 256 threads  (validated R13)
// ---------------------------------------------------------------------------
__global__ __launch_bounds__(256) void k3_alpha(
    const float* __restrict__ W1, const float* __restrict__ b1,
    const float* __restrict__ W2, const float* __restrict__ b2,
    const float* __restrict__ h_seq, float* __restrict__ out_alpha)
{
  const int tid = threadIdx.x;
  const int b = blockIdx.x >> 2, c = blockIdx.x & 3;
  const int sbeg = c * 50, send = sbeg + 50;
  __shared__ float4 hb4[2][DV_ / 4];
  __shared__ float red[4];
  const int grp = tid >> 7, d = tid & 127;
  float w1r[DV_];
  {
    const float4* wr = reinterpret_cast<const float4*>(W1 + (size_t)d * DV_);
#pragma unroll
    for (int k = 0; k < DV_ / 4; ++k) {
      float4 t4 = wr[k];
      w1r[4 * k] = t4.x; w1r[4 * k + 1] = t4.y;
      w1r[4 * k + 2] = t4.z; w1r[4 * k + 3] = t4.w;
    }
  }
  const float b1v = b1[d], w2v = W2[d], b2v = b2[0];
  float* hb = reinterpret_cast<float*>(hb4[grp]);
  for (int s = sbeg; s < send; s += 2) {
    const int ss = s + grp;
    hb[d] = h_seq[((size_t)(b * S_ + ss)) * DV_ + d];
    __syncthreads();
    float y0 = b1v, y1 = 0, y2 = 0, y3 = 0;
#pragma unroll
    for (int k = 0; k < DV_ / 4; ++k) {
      float4 hv = hb4[grp][k];
      y0 += w1r[4 * k + 0] * hv.x; y1 += w1r[4 * k + 1] * hv.y;
      y2 += w1r[4 * k + 2] * hv.z; y3 += w1r[4 * k + 3] * hv.w;
    }
    float part = w2v * fmaxf((y0 + y1) + (y2 + y3), 0.f);
#pragma unroll
    for (int off = 1; off < 64; off <<= 1) part += __shfl_xor(part, off);
    if ((tid & 63) == 0) red[tid >> 6] = part;
    __syncthreads();
    if (d == 0) out_alpha[b * S_ + ss] = red[2 * grp] + red[2 * grp + 1] + b2v;
    __syncthreads();
  }
}

extern "C" void kernel_launch(void* const* d_in, const int* in_sizes, int n_in,
                              void* d_out, int out_size, void* d_ws, size_t ws_size,
                              hipStream_t stream) {
  const int* c2_seq = (const int*)d_in[1];
  const int* d_seq = (const int*)d_in[3];
  const int* r_seq = (const int*)d_in[4];
  const float* D_emb = (const float*)d_in[5];
  const float* v_d = (const float*)d_in[6];
  const float* v_c2 = (const float*)d_in[7];
  const float* R_emb = (const float*)d_in[8];
  const float* W_ih = (const float*)d_in[9];
  const float* W_hh = (const float*)d_in[10];
  const float* b_ih = (const float*)d_in[11];
  const float* b_hh = (const float*)d_in[12];
  const float* W1 = (const float*)d_in[13];
  const float* b1 = (const float*)d_in[14];
  const float* W2 = (const float*)d_in[15];
  const float* b2 = (const float*)d_in[16];
  const float* W3 = (const float*)d_in[17];
  const float* b3 = (const float*)d_in[18];
  const float* W4 = (const float*)d_in[19];
  const float* b4 = (const float*)d_in[20];

  float* out = (float*)d_out;
  float* out_alpha = out;                                  // [B,S]
  float* out_h = out + B_ * S_;                            // [B,S,DV]
  float* out_c2 = out + B_ * S_ + (size_t)B_ * S_ * DV_;   // [B,S,NC2]
  float* vals_ws = (float*)d_ws;                           // [B*S] floats

  k_scan<<<dim3(B_), dim3(256), 0, stream>>>(
      c2_seq, d_seq, r_seq, D_emb, v_d, v_c2, R_emb, W3, b3, W4, b4, vals_ws);
  k2_gru_fill<<<dim3(B_ + B_ * NFCH), dim3(512), 0, stream>>>(
      c2_seq, d_seq, r_seq, D_emb, v_d, R_emb, W_ih, W_hh, b_ih, b_hh,
      vals_ws, out_h, out_c2);
  k3_alpha<<<dim3(256), dim3(256), 0, stream>>>(
      W1, b1, W2, b2, out_h, out_alpha);
}

// Round 18
// 155.228 us; speedup vs baseline: 1.8244x; 1.2425x over previous
//
#include <hip/hip_runtime.h>

namespace {
constexpr int B_ = 64, S_ = 200, DV_ = 128, NC2_ = 4096;
}

typedef float f4v __attribute__((ext_vector_type(4)));
typedef float f32x4 __attribute__((ext_vector_type(4)));
typedef _Float16 half8 __attribute__((ext_vector_type(8)));

// LDS-only barrier: no vmcnt drain.
__device__ __forceinline__ void lds_sync() {
  asm volatile("s_waitcnt lgkmcnt(0)\n\ts_barrier" ::: "memory");
}

// ---------------------------------------------------------------------------
// K1: blocks [0,64):   GRU per batch via broadcast-MFMA (R12 structure,
//                      512 threads, in-loop h store).
//     blocks [64,128): per-batch {parallel scan (thread-per-event, R14
//                      structure) -> register-resident row streaming fill}.
//                      Scan->fill dependency is INTRA-block (safe), and the
//                      whole scan+fill pipeline hides under the GRU.
// ---------------------------------------------------------------------------
__global__ __launch_bounds__(512, 1) void k1_gru_scanfill(
    const int* __restrict__ c2_seq, const int* __restrict__ d_seq,
    const int* __restrict__ r_seq, const float* __restrict__ D_emb,
    const float* __restrict__ v_d, const float* __restrict__ v_c2,
    const float* __restrict__ R_emb,
    const float* __restrict__ W_ih, const float* __restrict__ W_hh,
    const float* __restrict__ b_ih, const float* __restrict__ b_hh,
    const float* __restrict__ W3, const float* __restrict__ b3,
    const float* __restrict__ W4, const float* __restrict__ b4,
    float* __restrict__ out_h, float* __restrict__ out_c2)
{
  __shared__ __align__(16) char smem[18944];
  const int tid = threadIdx.x;

  if (blockIdx.x < B_) {
    // ------------------ GRU for batch b ------------------
    const int b = blockIdx.x;
    _Float16* hist = reinterpret_cast<_Float16*>(smem);          // [2][128] f16
    float* gl = reinterpret_cast<float*>(smem + 512);            // [200]
    int* rl = reinterpret_cast<int*>(smem + 1312);               // [200]
    float* u_l = reinterpret_cast<float*>(smem + 2112);          // [384] x4
    float* p0_l = u_l + 384;
    float* p1_l = p0_l + 384;
    float* bh_l = p1_l + 384;

    for (int i = tid; i < S_; i += 512) {
      gl[i] = D_emb[d_seq[b * S_ + i]];
      rl[i] = r_seq[b * S_ + i];
    }
    if (tid < 256) reinterpret_cast<_Float16*>(hist)[tid] = (_Float16)0.f;

    // collapsed input projections per gate row -> LDS
    if (tid < 384) {
      const int row = tid;
      const float4* wi =
          reinterpret_cast<const float4*>(W_ih + (size_t)row * 2 * DV_);
      const float4* vd4 = reinterpret_cast<const float4*>(v_d);
      const float4* re4 = reinterpret_cast<const float4*>(R_emb);
      float uu = 0.f, pp0 = 0.f, pp1 = 0.f;
#pragma unroll 8
      for (int k = 0; k < DV_ / 4; ++k) {
        float4 a = wi[k], vv = vd4[k];
        uu += a.x * vv.x + a.y * vv.y + a.z * vv.z + a.w * vv.w;
        float4 c = wi[DV_ / 4 + k];
        float4 r0 = re4[k], r1 = re4[DV_ / 4 + k];
        pp0 += c.x * r0.x + c.y * r0.y + c.z * r0.z + c.w * r0.w;
        pp1 += c.x * r1.x + c.y * r1.y + c.z * r1.z + c.w * r1.w;
      }
      const float bi = b_ih[row];
      u_l[row] = uu; p0_l[row] = pp0 + bi; p1_l[row] = pp1 + bi;
      bh_l[row] = b_hh[row];
    }

    // B-fragments (W_hh^T): lane l holds B[k=(l>>4)*8+j][col=l&15].
    const int w = tid >> 6, l = tid & 63;
    const int col = l & 15, kg = l >> 4;
    const int d = 16 * w + col;
    half8 bf[3][4];
#pragma unroll
    for (int g = 0; g < 3; ++g) {
      const float* wr = W_hh + (size_t)(g * DV_ + d) * DV_;
#pragma unroll
      for (int kt = 0; kt < 4; ++kt) {
        const int k0 = kt * 32 + kg * 8;
        const float4 lo = *reinterpret_cast<const float4*>(wr + k0);
        const float4 hi = *reinterpret_cast<const float4*>(wr + k0 + 4);
        half8 hb;
        hb[0] = (_Float16)lo.x; hb[1] = (_Float16)lo.y;
        hb[2] = (_Float16)lo.z; hb[3] = (_Float16)lo.w;
        hb[4] = (_Float16)hi.x; hb[5] = (_Float16)hi.y;
        hb[6] = (_Float16)hi.z; hb[7] = (_Float16)hi.w;
        bf[g][kt] = hb;
      }
    }
    __syncthreads();

    float u3[3], p03[3], p13[3], bh3[3];
#pragma unroll
    for (int g = 0; g < 3; ++g) {
      u3[g] = u_l[g * DV_ + d];
      p03[g] = p0_l[g * DV_ + d];
      p13[g] = p1_l[g * DV_ + d];
      bh3[g] = bh_l[g * DV_ + d];
    }
    float hprev = 0.f;
    float gv = gl[0];
    int rv = rl[0];

    float* outp = out_h + (size_t)b * S_ * DV_ + d;
    for (int t = 0; t < S_; ++t) {
      const int cur = t & 1;
      half8 af[4];
#pragma unroll
      for (int kt = 0; kt < 4; ++kt)
        af[kt] = *reinterpret_cast<const half8*>(&hist[cur * DV_ + kt * 32 + kg * 8]);
      f32x4 a0 = {0.f, 0.f, 0.f, 0.f}, a1 = a0, a2 = a0;
#pragma unroll
      for (int kt = 0; kt < 4; ++kt) {
        a0 = __builtin_amdgcn_mfma_f32_16x16x32_f16(af[kt], bf[0][kt], a0, 0, 0, 0);
        a1 = __builtin_amdgcn_mfma_f32_16x16x32_f16(af[kt], bf[1][kt], a1, 0, 0, 0);
        a2 = __builtin_amdgcn_mfma_f32_16x16x32_f16(af[kt], bf[2][kt], a2, 0, 0, 0);
      }
      const float xr = gv * u3[0] + (rv ? p13[0] : p03[0]);
      const float xz = gv * u3[1] + (rv ? p13[1] : p03[1]);
      const float xn = gv * u3[2] + (rv ? p13[2] : p03[2]);
      const float r = 1.f / (1.f + __expf(-(xr + a0[0] + bh3[0])));
      const float z = 1.f / (1.f + __expf(-(xz + a1[0] + bh3[1])));
      const float nx = xn + r * (a2[0] + bh3[2]);
      const float e2 = __expf(2.f * nx);
      const float n = (e2 - 1.f) / (e2 + 1.f);
      const float hnew = (1.f - z) * n + z * hprev;
      hprev = hnew;
      if (kg == 0) {
        outp[(size_t)t * DV_] = hnew;                 // fire-and-forget f32
        hist[(cur ^ 1) * DV_ + d] = (_Float16)hnew;
      }
      if (t + 1 < S_) { gv = gl[t + 1]; rv = rl[t + 1]; }
      lds_sync();
    }
  } else {
    // ------------- per-batch parallel scan + streaming fill -------------
    const int b = blockIdx.x - B_;
    float* a3s = reinterpret_cast<float*>(smem);            // [128] x5
    float* u3s = a3s + DV_;
    float* q0s = u3s + DV_;
    float* q1s = q0s + DV_;
    float* w4s = q1s + DV_;
    float* vals = w4s + DV_;                                // [200]
    float* gl = vals + S_;                                  // [200]
    int* rl = reinterpret_cast<int*>(gl + S_);
    int* jl = rl + S_;
    int* prevs = jl + S_;
    int* done = prevs + S_;
    int* nresp = done + S_;

    if (tid == 0) *nresp = 0;
    for (int i = tid; i < S_; i += 512) {
      gl[i] = D_emb[d_seq[b * S_ + i]];
      rl[i] = r_seq[b * S_ + i];
      jl[i] = c2_seq[b * S_ + i];
      done[i] = 0;
    }
    if (tid < DV_) {
      const int d = tid;
      const float4* w3r = reinterpret_cast<const float4*>(W3 + (size_t)d * 3 * DV_);
      const float4* vc4 = reinterpret_cast<const float4*>(v_c2);
      const float4* vd4 = reinterpret_cast<const float4*>(v_d);
      const float4* re4 = reinterpret_cast<const float4*>(R_emb);
      float a3 = 0, u3 = 0, q0 = 0, q1 = 0;
#pragma unroll 8
      for (int k = 0; k < DV_ / 4; ++k) {
        float4 a = w3r[k], cc = vc4[k];
        a3 += a.x * cc.x + a.y * cc.y + a.z * cc.z + a.w * cc.w;
        float4 u = w3r[DV_ / 4 + k], dd = vd4[k];
        u3 += u.x * dd.x + u.y * dd.y + u.z * dd.z + u.w * dd.w;
        float4 cq = w3r[2 * (DV_ / 4) + k];
        float4 r0 = re4[k], r1 = re4[DV_ / 4 + k];
        q0 += cq.x * r0.x + cq.y * r0.y + cq.z * r0.z + cq.w * r0.w;
        q1 += cq.x * r1.x + cq.y * r1.y + cq.z * r1.z + cq.w * r1.w;
      }
      const float bb = b3[d];
      a3s[d] = a3; u3s[d] = u3; q0s[d] = q0 + bb; q1s[d] = q1 + bb;
      w4s[d] = W4[d];
    }
    __syncthreads();
    if (tid < S_) {
      const int jj = jl[tid];
      int p = -1;
      for (int q = tid - 1; q >= 0; --q)
        if (jl[q] == jj) { p = q; break; }
      prevs[tid] = p;
    }
    const float b4v = b4[0];
    __syncthreads();

    // thread-per-event wavefront resolution (R14-validated)
    const int t = tid;
    const float gv = (t < S_) ? gl[t] : 0.f;
    const int rv = (t < S_) ? rl[t] : 0;
    const int p = (t < S_) ? prevs[t] : -1;
    bool mine_done = (t >= S_);

    for (int round = 0; round < S_; ++round) {
      float myval = 0.f;
      bool computed = false;
      if (!mine_done && (p < 0 || done[p])) {
        const float beta = (p < 0) ? 0.f : vals[p];
        const float4* a34 = reinterpret_cast<const float4*>(a3s);
        const float4* u34 = reinterpret_cast<const float4*>(u3s);
        const float4* q04 = reinterpret_cast<const float4*>(q0s);
        const float4* q14 = reinterpret_cast<const float4*>(q1s);
        const float4* w44 = reinterpret_cast<const float4*>(w4s);
        float acc = 0.f;
#pragma unroll 8
        for (int k = 0; k < DV_ / 4; ++k) {
          float4 a = a34[k], u = u34[k];
          float4 q = rv ? q14[k] : q04[k];
          float4 ww = w44[k];
          float h0 = beta * a.x + gv * u.x + q.x;
          float h1 = beta * a.y + gv * u.y + q.y;
          float h2 = beta * a.z + gv * u.z + q.z;
          float h3 = beta * a.w + gv * u.w + q.w;
          acc += ww.x * fmaxf(h0, 0.f) + ww.y * fmaxf(h1, 0.f) +
                 ww.z * fmaxf(h2, 0.f) + ww.w * fmaxf(h3, 0.f);
        }
        myval = acc + b4v;
        computed = true;
      }
      __syncthreads();
      if (computed) {
        vals[t] = myval;
        done[t] = 1;
        mine_done = true;
        atomicAdd(nresp, 1);
      }
      __syncthreads();
      if (*nresp >= S_) break;
    }
    __syncthreads();

    // ---------- streaming fill: all 200 rows from this one block ----------
    // thread owns 8 columns: float4 indices f = tid + jj*512, jj=0..1
    f4v v0 = {0.f, 0.f, 0.f, 0.f}, v1 = v0;
    f4v* dst4 = reinterpret_cast<f4v*>(out_c2 + (size_t)b * S_ * NC2_);
    for (int s = 0; s < S_; ++s) {
      const int j_ = jl[s];
      const int f_ = j_ >> 2;
      if ((f_ & 511) == tid) {
        const float vv_ = vals[s];
        const int rr_ = f_ >> 9, q_ = j_ & 3;
        if (rr_ == 0) {
          if (q_ == 0) v0.x = vv_; else if (q_ == 1) v0.y = vv_;
          else if (q_ == 2) v0.z = vv_; else v0.w = vv_;
        } else {
          if (q_ == 0) v1.x = vv_; else if (q_ == 1) v1.y = vv_;
          else if (q_ == 2) v1.z = vv_; else v1.w = vv_;
        }
      }
      f4v* drow = dst4 + (size_t)s * (NC2_ / 4);
      __builtin_nontemporal_store(v0, drow + tid);
      __builtin_nontemporal_store(v1, drow + tid + 512);
    }
  }
}

// ---------------------------------------------------------------------------
// K2: alpha MLP, (b, 50-row chunk), 256 blocks x 256 threads  (validated R13)
// ---------------------------------------------------------------------------
__global__ __launch_bounds__(256) void k2_alpha(
    const float* __restrict__ W1, const float* __restrict__ b1,
    const float* __restrict__ W2, const float* __restrict__ b2,
    const float* __restrict__ h_seq, float* __restrict__ out_alpha)
{
  const int tid = threadIdx.x;
  const int b = blockIdx.x >> 2, c = blockIdx.x & 3;
  const int sbeg = c * 50, send = sbeg + 50;
  __shared__ float4 hb4[2][DV_ / 4];
  __shared__ float red[4];
  const int grp = tid >> 7, d = tid & 127;
  float w1r[DV_];
  {
    const float4* wr = reinterpret_cast<const float4*>(W1 + (size_t)d * DV_);
#pragma unroll
    for (int k = 0; k < DV_ / 4; ++k) {
      float4 t4 = wr[k];
      w1r[4 * k] = t4.x; w1r[4 * k + 1] = t4.y;
      w1r[4 * k + 2] = t4.z; w1r[4 * k + 3] = t4.w;
    }
  }
  const float b1v = b1[d], w2v = W2[d], b2v = b2[0];
  float* hb = reinterpret_cast<float*>(hb4[grp]);
  for (int s = sbeg; s < send; s += 2) {
    const int ss = s + grp;
    hb[d] = h_seq[((size_t)(b * S_ + ss)) * DV_ + d];
    __syncthreads();
    float y0 = b1v, y1 = 0, y2 = 0, y3 = 0;
#pragma unroll
    for (int k = 0; k < DV_ / 4; ++k) {
      float4 hv = hb4[grp][k];
      y0 += w1r[4 * k + 0] * hv.x; y1 += w1r[4 * k + 1] * hv.y;
      y2 += w1r[4 * k + 2] * hv.z; y3 += w1r[4 * k + 3] * hv.w;
    }
    float part = w2v * fmaxf((y0 + y1) + (y2 + y3), 0.f);
#pragma unroll
    for (int off = 1; off < 64; off <<= 1) part += __shfl_xor(part, off);
    if ((tid & 63) == 0) red[tid >> 6] = part;
    __syncthreads();
    if (d == 0) out_alpha[b * S_ + ss] = red[2 * grp] + red[2 * grp + 1] + b2v;
    __syncthreads();
  }
}

extern "C" void kernel_launch(void* const* d_in, const int* in_sizes, int n_in,
                              void* d_out, int out_size, void* d_ws, size_t ws_size,
                              hipStream_t stream) {
  const int* c2_seq = (const int*)d_in[1];
  const int* d_seq = (const int*)d_in[3];
  const int* r_seq = (const int*)d_in[4];
  const float* D_emb = (const float*)d_in[5];
  const float* v_d = (const float*)d_in[6];
  const float* v_c2 = (const float*)d_in[7];
  const float* R_emb = (const float*)d_in[8];
  const float* W_ih = (const float*)d_in[9];
  const float* W_hh = (const float*)d_in[10];
  const float* b_ih = (const float*)d_in[11];
  const float* b_hh = (const float*)d_in[12];
  const float* W1 = (const float*)d_in[13];
  const float* b1 = (const float*)d_in[14];
  const float* W2 = (const float*)d_in[15];
  const float* b2 = (const float*)d_in[16];
  const float* W3 = (const float*)d_in[17];
  const float* b3 = (const float*)d_in[18];
  const float* W4 = (const float*)d_in[19];
  const float* b4 = (const float*)d_in[20];

  float* out = (float*)d_out;
  float* out_alpha = out;                                  // [B,S]
  float* out_h = out + B_ * S_;                            // [B,S,DV]
  float* out_c2 = out + B_ * S_ + (size_t)B_ * S_ * DV_;   // [B,S,NC2]

  k1_gru_scanfill<<<dim3(2 * B_), dim3(512), 0, stream>>>(
      c2_seq, d_seq, r_seq, D_emb, v_d, v_c2, R_emb, W_ih, W_hh, b_ih, b_hh,
      W3, b3, W4, b4, out_h, out_c2);
  k2_alpha<<<dim3(256), dim3(256), 0, stream>>>(
      W1, b1, W2, b2, out_h, out_alpha);
}

// Round 19
// 150.554 us; speedup vs baseline: 1.8811x; 1.0310x over previous
//
#include <hip/hip_runtime.h>

namespace {
constexpr int B_ = 64, S_ = 200, DV_ = 128, NC2_ = 4096;
}

typedef float f4v __attribute__((ext_vector_type(4)));
typedef float f32x4 __attribute__((ext_vector_type(4)));
typedef _Float16 half8 __attribute__((ext_vector_type(8)));
typedef _Float16 h2v __attribute__((ext_vector_type(2)));

#if defined(__has_builtin)
#if __has_builtin(__builtin_amdgcn_fdot2)
#define HAVE_FDOT2 1
#endif
#endif

__device__ __forceinline__ float dot2acc(h2v a, h2v b, float c) {
#ifdef HAVE_FDOT2
  return __builtin_amdgcn_fdot2(a, b, c, false);
#else
  return c + (float)a.x * (float)b.x + (float)a.y * (float)b.y;
#endif
}

// LDS-only barrier: no vmcnt drain.
__device__ __forceinline__ void lds_sync() {
  asm volatile("s_waitcnt lgkmcnt(0)\n\ts_barrier" ::: "memory");
}

// Full-wave (64) sum via DPP; broadcast via readlane 63.
__device__ __forceinline__ float wave_sum_bcast(float x) {
  float a = x;
  int s = __builtin_bit_cast(int, a);
  s = __builtin_amdgcn_update_dpp(0, s, 0x111, 0xf, 0xf, true);
  a += __builtin_bit_cast(float, s);
  s = __builtin_bit_cast(int, a);
  s = __builtin_amdgcn_update_dpp(0, s, 0x112, 0xf, 0xf, true);
  a += __builtin_bit_cast(float, s);
  s = __builtin_bit_cast(int, a);
  s = __builtin_amdgcn_update_dpp(0, s, 0x114, 0xf, 0xf, true);
  a += __builtin_bit_cast(float, s);
  s = __builtin_bit_cast(int, a);
  s = __builtin_amdgcn_update_dpp(0, s, 0x118, 0xf, 0xf, true);
  a += __builtin_bit_cast(float, s);
  s = __builtin_bit_cast(int, a);
  s = __builtin_amdgcn_update_dpp(0, s, 0x142, 0xf, 0xf, true);
  a += __builtin_bit_cast(float, s);
  s = __builtin_bit_cast(int, a);
  s = __builtin_amdgcn_update_dpp(0, s, 0x143, 0xf, 0xf, true);
  a += __builtin_bit_cast(float, s);
  s = __builtin_bit_cast(int, a);
  return __builtin_bit_cast(float, __builtin_amdgcn_readlane(s, 63));
}

// ---------------------------------------------------------------------------
// K1: blocks [0,64):   GRU per batch (R17 loop, unchanged) + f16 full history
//                      append + fused alpha tail (R14-validated).
//     blocks [64,128): per-batch {parallel scan -> streaming fill} (R17).
// ---------------------------------------------------------------------------
__global__ __launch_bounds__(512, 1) void k1_main(
    const int* __restrict__ c2_seq, const int* __restrict__ d_seq,
    const int* __restrict__ r_seq, const float* __restrict__ D_emb,
    const float* __restrict__ v_d, const float* __restrict__ v_c2,
    const float* __restrict__ R_emb,
    const float* __restrict__ W_ih, const float* __restrict__ W_hh,
    const float* __restrict__ b_ih, const float* __restrict__ b_hh,
    const float* __restrict__ W1, const float* __restrict__ b1,
    const float* __restrict__ W2, const float* __restrict__ b2,
    const float* __restrict__ W3, const float* __restrict__ b3,
    const float* __restrict__ W4, const float* __restrict__ b4,
    float* __restrict__ out_alpha, float* __restrict__ out_h,
    float* __restrict__ out_c2)
{
  __shared__ __align__(16) char smem[18944 + S_ * DV_ * 2];
  const int tid = threadIdx.x;

  if (blockIdx.x < B_) {
    // ------------------ GRU for batch b ------------------
    const int b = blockIdx.x;
    _Float16* hist = reinterpret_cast<_Float16*>(smem);          // [2][128] f16
    float* gl = reinterpret_cast<float*>(smem + 512);            // [200]
    int* rl = reinterpret_cast<int*>(smem + 1312);               // [200]
    float* u_l = reinterpret_cast<float*>(smem + 2112);          // [384] x4
    float* p0_l = u_l + 384;
    float* p1_l = p0_l + 384;
    float* bh_l = p1_l + 384;
    _Float16* fullh = reinterpret_cast<_Float16*>(smem + 18944); // [200][128]

    for (int i = tid; i < S_; i += 512) {
      gl[i] = D_emb[d_seq[b * S_ + i]];
      rl[i] = r_seq[b * S_ + i];
    }
    if (tid < 256) reinterpret_cast<_Float16*>(hist)[tid] = (_Float16)0.f;

    // collapsed input projections per gate row -> LDS
    if (tid < 384) {
      const int row = tid;
      const float4* wi =
          reinterpret_cast<const float4*>(W_ih + (size_t)row * 2 * DV_);
      const float4* vd4 = reinterpret_cast<const float4*>(v_d);
      const float4* re4 = reinterpret_cast<const float4*>(R_emb);
      float uu = 0.f, pp0 = 0.f, pp1 = 0.f;
#pragma unroll 8
      for (int k = 0; k < DV_ / 4; ++k) {
        float4 a = wi[k], vv = vd4[k];
        uu += a.x * vv.x + a.y * vv.y + a.z * vv.z + a.w * vv.w;
        float4 c = wi[DV_ / 4 + k];
        float4 r0 = re4[k], r1 = re4[DV_ / 4 + k];
        pp0 += c.x * r0.x + c.y * r0.y + c.z * r0.z + c.w * r0.w;
        pp1 += c.x * r1.x + c.y * r1.y + c.z * r1.z + c.w * r1.w;
      }
      const float bi = b_ih[row];
      u_l[row] = uu; p0_l[row] = pp0 + bi; p1_l[row] = pp1 + bi;
      bh_l[row] = b_hh[row];
    }

    // B-fragments (W_hh^T): lane l holds B[k=(l>>4)*8+j][col=l&15].
    const int w = tid >> 6, l = tid & 63;
    const int col = l & 15, kg = l >> 4;
    const int d = 16 * w + col;
    half8 bf[3][4];
#pragma unroll
    for (int g = 0; g < 3; ++g) {
      const float* wr = W_hh + (size_t)(g * DV_ + d) * DV_;
#pragma unroll
      for (int kt = 0; kt < 4; ++kt) {
        const int k0 = kt * 32 + kg * 8;
        const float4 lo = *reinterpret_cast<const float4*>(wr + k0);
        const float4 hi = *reinterpret_cast<const float4*>(wr + k0 + 4);
        half8 hb;
        hb[0] = (_Float16)lo.x; hb[1] = (_Float16)lo.y;
        hb[2] = (_Float16)lo.z; hb[3] = (_Float16)lo.w;
        hb[4] = (_Float16)hi.x; hb[5] = (_Float16)hi.y;
        hb[6] = (_Float16)hi.z; hb[7] = (_Float16)hi.w;
        bf[g][kt] = hb;
      }
    }
    __syncthreads();

    float u3[3], p03[3], p13[3], bh3[3];
#pragma unroll
    for (int g = 0; g < 3; ++g) {
      u3[g] = u_l[g * DV_ + d];
      p03[g] = p0_l[g * DV_ + d];
      p13[g] = p1_l[g * DV_ + d];
      bh3[g] = bh_l[g * DV_ + d];
    }
    float hprev = 0.f;
    float gv = gl[0];
    int rv = rl[0];

    float* outp = out_h + (size_t)b * S_ * DV_ + d;
    for (int t = 0; t < S_; ++t) {
      const int cur = t & 1;
      half8 af[4];
#pragma unroll
      for (int kt = 0; kt < 4; ++kt)
        af[kt] = *reinterpret_cast<const half8*>(&hist[cur * DV_ + kt * 32 + kg * 8]);
      f32x4 a0 = {0.f, 0.f, 0.f, 0.f}, a1 = a0, a2 = a0;
#pragma unroll
      for (int kt = 0; kt < 4; ++kt) {
        a0 = __builtin_amdgcn_mfma_f32_16x16x32_f16(af[kt], bf[0][kt], a0, 0, 0, 0);
        a1 = __builtin_amdgcn_mfma_f32_16x16x32_f16(af[kt], bf[1][kt], a1, 0, 0, 0);
        a2 = __builtin_amdgcn_mfma_f32_16x16x32_f16(af[kt], bf[2][kt], a2, 0, 0, 0);
      }
      const float xr = gv * u3[0] + (rv ? p13[0] : p03[0]);
      const float xz = gv * u3[1] + (rv ? p13[1] : p03[1]);
      const float xn = gv * u3[2] + (rv ? p13[2] : p03[2]);
      const float r = 1.f / (1.f + __expf(-(xr + a0[0] + bh3[0])));
      const float z = 1.f / (1.f + __expf(-(xz + a1[0] + bh3[1])));
      const float nx = xn + r * (a2[0] + bh3[2]);
      const float e2 = __expf(2.f * nx);
      const float n = (e2 - 1.f) / (e2 + 1.f);
      const float hnew = (1.f - z) * n + z * hprev;
      hprev = hnew;
      if (kg == 0) {
        outp[(size_t)t * DV_] = hnew;                 // fire-and-forget f32
        const _Float16 hf = (_Float16)hnew;
        hist[(cur ^ 1) * DV_ + d] = hf;
        fullh[t * DV_ + d] = hf;                      // append history
      }
      if (t + 1 < S_) { gv = gl[t + 1]; rv = rl[t + 1]; }
      lds_sync();
    }

    // ---------- fused alpha tail: 8 waves, rows s = w + 8*i ----------
    const int lane = l;
    h2v w1L[64], w1H[64];
    {
      const float4* wrL = reinterpret_cast<const float4*>(W1 + (size_t)lane * DV_);
      const float4* wrH = reinterpret_cast<const float4*>(W1 + (size_t)(lane + 64) * DV_);
#pragma unroll
      for (int k = 0; k < 32; ++k) {
        float4 tL = wrL[k], tH = wrH[k];
        h2v a, bq;
        a.x = (_Float16)tL.x; a.y = (_Float16)tL.y;
        bq.x = (_Float16)tL.z; bq.y = (_Float16)tL.w;
        w1L[2 * k] = a; w1L[2 * k + 1] = bq;
        a.x = (_Float16)tH.x; a.y = (_Float16)tH.y;
        bq.x = (_Float16)tH.z; bq.y = (_Float16)tH.w;
        w1H[2 * k] = a; w1H[2 * k + 1] = bq;
      }
    }
    const float b1L = b1[lane], b1H = b1[lane + 64];
    const float w2L = W2[lane], w2H = W2[lane + 64];
    const float b2v = b2[0];
    for (int s = w; s < S_; s += 8) {
      const float4* hb = reinterpret_cast<const float4*>(fullh + s * DV_);
      float yL = 0.f, yH = 0.f;
#pragma unroll
      for (int k = 0; k < 16; ++k) {
        float4 hv = hb[k];
        h2v h0 = __builtin_bit_cast(h2v, hv.x);
        h2v h1 = __builtin_bit_cast(h2v, hv.y);
        h2v h2 = __builtin_bit_cast(h2v, hv.z);
        h2v h3 = __builtin_bit_cast(h2v, hv.w);
        yL = dot2acc(w1L[4 * k + 0], h0, yL);
        yH = dot2acc(w1H[4 * k + 0], h0, yH);
        yL = dot2acc(w1L[4 * k + 1], h1, yL);
        yH = dot2acc(w1H[4 * k + 1], h1, yH);
        yL = dot2acc(w1L[4 * k + 2], h2, yL);
        yH = dot2acc(w1H[4 * k + 2], h2, yH);
        yL = dot2acc(w1L[4 * k + 3], h3, yL);
        yH = dot2acc(w1H[4 * k + 3], h3, yH);
      }
      const float part = w2L * fmaxf(yL + b1L, 0.f) + w2H * fmaxf(yH + b1H, 0.f);
      const float sum = wave_sum_bcast(part);
      if (lane == 0) out_alpha[b * S_ + s] = sum + b2v;
    }
  } else {
    // ------------- per-batch parallel scan + streaming fill -------------
    const int b = blockIdx.x - B_;
    float* a3s = reinterpret_cast<float*>(smem);            // [128] x5
    float* u3s = a3s + DV_;
    float* q0s = u3s + DV_;
    float* q1s = q0s + DV_;
    float* w4s = q1s + DV_;
    float* vals = w4s + DV_;                                // [200]
    float* gl = vals + S_;                                  // [200]
    int* rl = reinterpret_cast<int*>(gl + S_);
    int* jl = rl + S_;
    int* prevs = jl + S_;
    int* done = prevs + S_;
    int* nresp = done + S_;

    if (tid == 0) *nresp = 0;
    for (int i = tid; i < S_; i += 512) {
      gl[i] = D_emb[d_seq[b * S_ + i]];
      rl[i] = r_seq[b * S_ + i];
      jl[i] = c2_seq[b * S_ + i];
      done[i] = 0;
    }
    if (tid < DV_) {
      const int d = tid;
      const float4* w3r = reinterpret_cast<const float4*>(W3 + (size_t)d * 3 * DV_);
      const float4* vc4 = reinterpret_cast<const float4*>(v_c2);
      const float4* vd4 = reinterpret_cast<const float4*>(v_d);
      const float4* re4 = reinterpret_cast<const float4*>(R_emb);
      float a3 = 0, u3 = 0, q0 = 0, q1 = 0;
#pragma unroll 8
      for (int k = 0; k < DV_ / 4; ++k) {
        float4 a = w3r[k], cc = vc4[k];
        a3 += a.x * cc.x + a.y * cc.y + a.z * cc.z + a.w * cc.w;
        float4 u = w3r[DV_ / 4 + k], dd = vd4[k];
        u3 += u.x * dd.x + u.y * dd.y + u.z * dd.z + u.w * dd.w;
        float4 cq = w3r[2 * (DV_ / 4) + k];
        float4 r0 = re4[k], r1 = re4[DV_ / 4 + k];
        q0 += cq.x * r0.x + cq.y * r0.y + cq.z * r0.z + cq.w * r0.w;
        q1 += cq.x * r1.x + cq.y * r1.y + cq.z * r1.z + cq.w * r1.w;
      }
      const float bb = b3[d];
      a3s[d] = a3; u3s[d] = u3; q0s[d] = q0 + bb; q1s[d] = q1 + bb;
      w4s[d] = W4[d];
    }
    __syncthreads();
    if (tid < S_) {
      const int jj = jl[tid];
      int p = -1;
      for (int q = tid - 1; q >= 0; --q)
        if (jl[q] == jj) { p = q; break; }
      prevs[tid] = p;
    }
    const float b4v = b4[0];
    __syncthreads();

    // thread-per-event wavefront resolution (R14-validated)
    const int t = tid;
    const float gv = (t < S_) ? gl[t] : 0.f;
    const int rv = (t < S_) ? rl[t] : 0;
    const int p = (t < S_) ? prevs[t] : -1;
    bool mine_done = (t >= S_);

    for (int round = 0; round < S_; ++round) {
      float myval = 0.f;
      bool computed = false;
      if (!mine_done && (p < 0 || done[p])) {
        const float beta = (p < 0) ? 0.f : vals[p];
        const float4* a34 = reinterpret_cast<const float4*>(a3s);
        const float4* u34 = reinterpret_cast<const float4*>(u3s);
        const float4* q04 = reinterpret_cast<const float4*>(q0s);
        const float4* q14 = reinterpret_cast<const float4*>(q1s);
        const float4* w44 = reinterpret_cast<const float4*>(w4s);
        float acc = 0.f;
#pragma unroll 8
        for (int k = 0; k < DV_ / 4; ++k) {
          float4 a = a34[k], u = u34[k];
          float4 q = rv ? q14[k] : q04[k];
          float4 ww = w44[k];
          float h0 = beta * a.x + gv * u.x + q.x;
          float h1 = beta * a.y + gv * u.y + q.y;
          float h2 = beta * a.z + gv * u.z + q.z;
          float h3 = beta * a.w + gv * u.w + q.w;
          acc += ww.x * fmaxf(h0, 0.f) + ww.y * fmaxf(h1, 0.f) +
                 ww.z * fmaxf(h2, 0.f) + ww.w * fmaxf(h3, 0.f);
        }
        myval = acc + b4v;
        computed = true;
      }
      __syncthreads();
      if (computed) {
        vals[t] = myval;
        done[t] = 1;
        mine_done = true;
        atomicAdd(nresp, 1);
      }
      __syncthreads();
      if (*nresp >= S_) break;
    }
    __syncthreads();

    // ---------- streaming fill: all 200 rows from this one block ----------
    f4v v0 = {0.f, 0.f, 0.f, 0.f}, v1 = v0;
    f4v* dst4 = reinterpret_cast<f4v*>(out_c2 + (size_t)b * S_ * NC2_);
    for (int s = 0; s < S_; ++s) {
      const int j_ = jl[s];
      const int f_ = j_ >> 2;
      if ((f_ & 511) == tid) {
        const float vv_ = vals[s];
        const int rr_ = f_ >> 9, q_ = j_ & 3;
        if (rr_ == 0) {
          if (q_ == 0) v0.x = vv_; else if (q_ == 1) v0.y = vv_;
          else if (q_ == 2) v0.z = vv_; else v0.w = vv_;
        } else {
          if (q_ == 0) v1.x = vv_; else if (q_ == 1) v1.y = vv_;
          else if (q_ == 2) v1.z = vv_; else v1.w = vv_;
        }
      }
      f4v* drow = dst4 + (size_t)s * (NC2_ / 4);
      __builtin_nontemporal_store(v0, drow + tid);
      __builtin_nontemporal_store(v1, drow + tid + 512);
    }
  }
}

extern "C" void kernel_launch(void* const* d_in, const int* in_sizes, int n_in,
                              void* d_out, int out_size, void* d_ws, size_t ws_size,
                              hipStream_t stream) {
  const int* c2_seq = (const int*)d_in[1];
  const int* d_seq = (const int*)d_in[3];
  const int* r_seq = (const int*)d_in[4];
  const float* D_emb = (const float*)d_in[5];
  const float* v_d = (const float*)d_in[6];
  const float* v_c2 = (const float*)d_in[7];
  const float* R_emb = (const float*)d_in[8];
  const float* W_ih = (const float*)d_in[9];
  const float* W_hh = (const float*)d_in[10];
  const float* b_ih = (const float*)d_in[11];
  const float* b_hh = (const float*)d_in[12];
  const float* W1 = (const float*)d_in[13];
  const float* b1 = (const float*)d_in[14];
  const float* W2 = (const float*)d_in[15];
  const float* b2 = (const float*)d_in[16];
  const float* W3 = (const float*)d_in[17];
  const float* b3 = (const float*)d_in[18];
  const float* W4 = (const float*)d_in[19];
  const float* b4 = (const float*)d_in[20];

  float* out = (float*)d_out;
  float* out_alpha = out;                                  // [B,S]
  float* out_h = out + B_ * S_;                            // [B,S,DV]
  float* out_c2 = out + B_ * S_ + (size_t)B_ * S_ * DV_;   // [B,S,NC2]

  k1_main<<<dim3(2 * B_), dim3(512), 0, stream>>>(
      c2_seq, d_seq, r_seq, D_emb, v_d, v_c2, R_emb, W_ih, W_hh, b_ih, b_hh,
      W1, b1, W2, b2, W3, b3, W4, b4, out_alpha, out_h, out_c2);
}

// Round 20
// 134.531 us; speedup vs baseline: 2.1051x; 1.1191x over previous
//
#include <hip/hip_runtime.h>

namespace {
constexpr int B_ = 64, S_ = 200, DV_ = 128, NC2_ = 4096;
}

typedef float f4v __attribute__((ext_vector_type(4)));
typedef float f32x4 __attribute__((ext_vector_type(4)));
typedef _Float16 half8 __attribute__((ext_vector_type(8)));

// LDS-only barrier: no vmcnt drain.
__device__ __forceinline__ void lds_sync() {
  asm volatile("s_waitcnt lgkmcnt(0)\n\ts_barrier" ::: "memory");
}

// ---------------------------------------------------------------------------
// K1: blocks [0,64):   GRU per batch (R17 loop) + swizzled f16 history append
//                      + MFMA alpha tail (no per-lane weight arrays -> no
//                      scratch spill).
//     blocks [64,128): per-batch {parallel scan -> streaming fill} (R17).
// ---------------------------------------------------------------------------
__global__ __launch_bounds__(512, 1) void k1_main(
    const int* __restrict__ c2_seq, const int* __restrict__ d_seq,
    const int* __restrict__ r_seq, const float* __restrict__ D_emb,
    const float* __restrict__ v_d, const float* __restrict__ v_c2,
    const float* __restrict__ R_emb,
    const float* __restrict__ W_ih, const float* __restrict__ W_hh,
    const float* __restrict__ b_ih, const float* __restrict__ b_hh,
    const float* __restrict__ W1, const float* __restrict__ b1,
    const float* __restrict__ W2, const float* __restrict__ b2,
    const float* __restrict__ W3, const float* __restrict__ b3,
    const float* __restrict__ W4, const float* __restrict__ b4,
    float* __restrict__ out_alpha, float* __restrict__ out_h,
    float* __restrict__ out_c2)
{
  __shared__ __align__(16) char smem[18944 + 208 * DV_ * 2];
  const int tid = threadIdx.x;

  if (blockIdx.x < B_) {
    // ------------------ GRU for batch b ------------------
    const int b = blockIdx.x;
    _Float16* hist = reinterpret_cast<_Float16*>(smem);          // [2][128] f16
    float* gl = reinterpret_cast<float*>(smem + 512);            // [200]
    int* rl = reinterpret_cast<int*>(smem + 1312);               // [200]
    float* u_l = reinterpret_cast<float*>(smem + 2112);          // [384] x4
    float* p0_l = u_l + 384;
    float* p1_l = p0_l + 384;
    float* bh_l = p1_l + 384;
    _Float16* fullh = reinterpret_cast<_Float16*>(smem + 18944); // [208][128]

    for (int i = tid; i < S_; i += 512) {
      gl[i] = D_emb[d_seq[b * S_ + i]];
      rl[i] = r_seq[b * S_ + i];
    }
    if (tid < 256) reinterpret_cast<_Float16*>(hist)[tid] = (_Float16)0.f;
    // zero fullh rows 200..207 (tail tile padding)
    {
      uint* fz = reinterpret_cast<uint*>(fullh + 200 * DV_);
      for (int i = tid; i < 8 * DV_ / 2; i += 512) fz[i] = 0u;
    }

    // collapsed input projections per gate row -> LDS
    if (tid < 384) {
      const int row = tid;
      const float4* wi =
          reinterpret_cast<const float4*>(W_ih + (size_t)row * 2 * DV_);
      const float4* vd4 = reinterpret_cast<const float4*>(v_d);
      const float4* re4 = reinterpret_cast<const float4*>(R_emb);
      float uu = 0.f, pp0 = 0.f, pp1 = 0.f;
#pragma unroll 8
      for (int k = 0; k < DV_ / 4; ++k) {
        float4 a = wi[k], vv = vd4[k];
        uu += a.x * vv.x + a.y * vv.y + a.z * vv.z + a.w * vv.w;
        float4 c = wi[DV_ / 4 + k];
        float4 r0 = re4[k], r1 = re4[DV_ / 4 + k];
        pp0 += c.x * r0.x + c.y * r0.y + c.z * r0.z + c.w * r0.w;
        pp1 += c.x * r1.x + c.y * r1.y + c.z * r1.z + c.w * r1.w;
      }
      const float bi = b_ih[row];
      u_l[row] = uu; p0_l[row] = pp0 + bi; p1_l[row] = pp1 + bi;
      bh_l[row] = b_hh[row];
    }

    // B-fragments (W_hh^T): lane l holds B[k=(l>>4)*8+j][col=l&15].
    const int w = tid >> 6, l = tid & 63;
    const int col = l & 15, kg = l >> 4;
    const int d = 16 * w + col;
    half8 bf[3][4];
#pragma unroll
    for (int g = 0; g < 3; ++g) {
      const float* wr = W_hh + (size_t)(g * DV_ + d) * DV_;
#pragma unroll
      for (int kt = 0; kt < 4; ++kt) {
        const int k0 = kt * 32 + kg * 8;
        const float4 lo = *reinterpret_cast<const float4*>(wr + k0);
        const float4 hi = *reinterpret_cast<const float4*>(wr + k0 + 4);
        half8 hb;
        hb[0] = (_Float16)lo.x; hb[1] = (_Float16)lo.y;
        hb[2] = (_Float16)lo.z; hb[3] = (_Float16)lo.w;
        hb[4] = (_Float16)hi.x; hb[5] = (_Float16)hi.y;
        hb[6] = (_Float16)hi.z; hb[7] = (_Float16)hi.w;
        bf[g][kt] = hb;
      }
    }
    __syncthreads();

    float u3[3], p03[3], p13[3], bh3[3];
#pragma unroll
    for (int g = 0; g < 3; ++g) {
      u3[g] = u_l[g * DV_ + d];
      p03[g] = p0_l[g * DV_ + d];
      p13[g] = p1_l[g * DV_ + d];
      bh3[g] = bh_l[g * DV_ + d];
    }
    float hprev = 0.f;
    float gv = gl[0];
    int rv = rl[0];

    float* outp = out_h + (size_t)b * S_ * DV_ + d;
    for (int t = 0; t < S_; ++t) {
      const int cur = t & 1;
      half8 af[4];
#pragma unroll
      for (int kt = 0; kt < 4; ++kt)
        af[kt] = *reinterpret_cast<const half8*>(&hist[cur * DV_ + kt * 32 + kg * 8]);
      f32x4 a0 = {0.f, 0.f, 0.f, 0.f}, a1 = a0, a2 = a0;
#pragma unroll
      for (int kt = 0; kt < 4; ++kt) {
        a0 = __builtin_amdgcn_mfma_f32_16x16x32_f16(af[kt], bf[0][kt], a0, 0, 0, 0);
        a1 = __builtin_amdgcn_mfma_f32_16x16x32_f16(af[kt], bf[1][kt], a1, 0, 0, 0);
        a2 = __builtin_amdgcn_mfma_f32_16x16x32_f16(af[kt], bf[2][kt], a2, 0, 0, 0);
      }
      const float xr = gv * u3[0] + (rv ? p13[0] : p03[0]);
      const float xz = gv * u3[1] + (rv ? p13[1] : p03[1]);
      const float xn = gv * u3[2] + (rv ? p13[2] : p03[2]);
      const float r = 1.f / (1.f + __expf(-(xr + a0[0] + bh3[0])));
      const float z = 1.f / (1.f + __expf(-(xz + a1[0] + bh3[1])));
      const float nx = xn + r * (a2[0] + bh3[2]);
      const float e2 = __expf(2.f * nx);
      const float n = (e2 - 1.f) / (e2 + 1.f);
      const float hnew = (1.f - z) * n + z * hprev;
      hprev = hnew;
      if (kg == 0) {
        outp[(size_t)t * DV_] = hnew;                 // fire-and-forget f32
        const _Float16 hf = (_Float16)hnew;
        hist[(cur ^ 1) * DV_ + d] = hf;
        fullh[t * DV_ + (d ^ ((t & 7) << 3))] = hf;   // swizzled history
      }
      if (t + 1 < S_) { gv = gl[t + 1]; rv = rl[t + 1]; }
      lds_sync();
    }

    // ---------- MFMA alpha tail: y = fullh @ W1^T, 13 s-tiles ----------
    half8 bf1[4];
    {
      const float* wr1 = W1 + (size_t)d * DV_;
#pragma unroll
      for (int kt = 0; kt < 4; ++kt) {
        const int k0 = kt * 32 + kg * 8;
        const float4 lo = *reinterpret_cast<const float4*>(wr1 + k0);
        const float4 hi = *reinterpret_cast<const float4*>(wr1 + k0 + 4);
        half8 hb;
        hb[0] = (_Float16)lo.x; hb[1] = (_Float16)lo.y;
        hb[2] = (_Float16)lo.z; hb[3] = (_Float16)lo.w;
        hb[4] = (_Float16)hi.x; hb[5] = (_Float16)hi.y;
        hb[6] = (_Float16)hi.z; hb[7] = (_Float16)hi.w;
        bf1[kt] = hb;
      }
    }
    const float b1v = b1[d], w2v = W2[d], b2v = b2[0];
    float* alphaAcc = u_l;  // reuse dead LDS (384 floats >= 208)
    if (tid < 208) alphaAcc[tid] = b2v;
    lds_sync();
    for (int st = 0; st < 13; ++st) {
      const int row = 16 * st + col;   // A row = lane&15 (R10-verified)
      half8 af2[4];
#pragma unroll
      for (int kt = 0; kt < 4; ++kt) {
        const int c0 = (kt * 32 + kg * 8) ^ ((row & 7) << 3);
        af2[kt] = *reinterpret_cast<const half8*>(&fullh[row * DV_ + c0]);
      }
      f32x4 y = {0.f, 0.f, 0.f, 0.f};
#pragma unroll
      for (int kt = 0; kt < 4; ++kt)
        y = __builtin_amdgcn_mfma_f32_16x16x32_f16(af2[kt], bf1[kt], y, 0, 0, 0);
#pragma unroll
      for (int j = 0; j < 4; ++j) {
        float part = w2v * fmaxf(y[j] + b1v, 0.f);
        part += __shfl_xor(part, 1);
        part += __shfl_xor(part, 2);
        part += __shfl_xor(part, 4);
        part += __shfl_xor(part, 8);
        if (col == 0) atomicAdd(&alphaAcc[16 * st + 4 * kg + j], part);
      }
    }
    lds_sync();
    if (tid < S_) out_alpha[b * S_ + tid] = alphaAcc[tid];
  } else {
    // ------------- per-batch parallel scan + streaming fill -------------
    const int b = blockIdx.x - B_;
    float* a3s = reinterpret_cast<float*>(smem);            // [128] x5
    float* u3s = a3s + DV_;
    float* q0s = u3s + DV_;
    float* q1s = q0s + DV_;
    float* w4s = q1s + DV_;
    float* vals = w4s + DV_;                                // [200]
    float* gl = vals + S_;                                  // [200]
    int* rl = reinterpret_cast<int*>(gl + S_);
    int* jl = rl + S_;
    int* prevs = jl + S_;
    int* done = prevs + S_;
    int* nresp = done + S_;

    if (tid == 0) *nresp = 0;
    for (int i = tid; i < S_; i += 512) {
      gl[i] = D_emb[d_seq[b * S_ + i]];
      rl[i] = r_seq[b * S_ + i];
      jl[i] = c2_seq[b * S_ + i];
      done[i] = 0;
    }
    if (tid < DV_) {
      const int d = tid;
      const float4* w3r = reinterpret_cast<const float4*>(W3 + (size_t)d * 3 * DV_);
      const float4* vc4 = reinterpret_cast<const float4*>(v_c2);
      const float4* vd4 = reinterpret_cast<const float4*>(v_d);
      const float4* re4 = reinterpret_cast<const float4*>(R_emb);
      float a3 = 0, u3 = 0, q0 = 0, q1 = 0;
#pragma unroll 8
      for (int k = 0; k < DV_ / 4; ++k) {
        float4 a = w3r[k], cc = vc4[k];
        a3 += a.x * cc.x + a.y * cc.y + a.z * cc.z + a.w * cc.w;
        float4 u = w3r[DV_ / 4 + k], dd = vd4[k];
        u3 += u.x * dd.x + u.y * dd.y + u.z * dd.z + u.w * dd.w;
        float4 cq = w3r[2 * (DV_ / 4) + k];
        float4 r0 = re4[k], r1 = re4[DV_ / 4 + k];
        q0 += cq.x * r0.x + cq.y * r0.y + cq.z * r0.z + cq.w * r0.w;
        q1 += cq.x * r1.x + cq.y * r1.y + cq.z * r1.z + cq.w * r1.w;
      }
      const float bb = b3[d];
      a3s[d] = a3; u3s[d] = u3; q0s[d] = q0 + bb; q1s[d] = q1 + bb;
      w4s[d] = W4[d];
    }
    __syncthreads();
    if (tid < S_) {
      const int jj = jl[tid];
      int p = -1;
      for (int q = tid - 1; q >= 0; --q)
        if (jl[q] == jj) { p = q; break; }
      prevs[tid] = p;
    }
    const float b4v = b4[0];
    __syncthreads();

    // thread-per-event wavefront resolution (R14-validated)
    const int t = tid;
    const float gv = (t < S_) ? gl[t] : 0.f;
    const int rv = (t < S_) ? rl[t] : 0;
    const int p = (t < S_) ? prevs[t] : -1;
    bool mine_done = (t >= S_);

    for (int round = 0; round < S_; ++round) {
      float myval = 0.f;
      bool computed = false;
      if (!mine_done && (p < 0 || done[p])) {
        const float beta = (p < 0) ? 0.f : vals[p];
        const float4* a34 = reinterpret_cast<const float4*>(a3s);
        const float4* u34 = reinterpret_cast<const float4*>(u3s);
        const float4* q04 = reinterpret_cast<const float4*>(q0s);
        const float4* q14 = reinterpret_cast<const float4*>(q1s);
        const float4* w44 = reinterpret_cast<const float4*>(w4s);
        float acc = 0.f;
#pragma unroll 8
        for (int k = 0; k < DV_ / 4; ++k) {
          float4 a = a34[k], u = u34[k];
          float4 q = rv ? q14[k] : q04[k];
          float4 ww = w44[k];
          float h0 = beta * a.x + gv * u.x + q.x;
          float h1 = beta * a.y + gv * u.y + q.y;
          float h2 = beta * a.z + gv * u.z + q.z;
          float h3 = beta * a.w + gv * u.w + q.w;
          acc += ww.x * fmaxf(h0, 0.f) + ww.y * fmaxf(h1, 0.f) +
                 ww.z * fmaxf(h2, 0.f) + ww.w * fmaxf(h3, 0.f);
        }
        myval = acc + b4v;
        computed = true;
      }
      __syncthreads();
      if (computed) {
        vals[t] = myval;
        done[t] = 1;
        mine_done = true;
        atomicAdd(nresp, 1);
      }
      __syncthreads();
      if (*nresp >= S_) break;
    }
    __syncthreads();

    // ---------- streaming fill: all 200 rows from this one block ----------
    f4v v0 = {0.f, 0.f, 0.f, 0.f}, v1 = v0;
    f4v* dst4 = reinterpret_cast<f4v*>(out_c2 + (size_t)b * S_ * NC2_);
    for (int s = 0; s < S_; ++s) {
      const int j_ = jl[s];
      const int f_ = j_ >> 2;
      if ((f_ & 511) == tid) {
        const float vv_ = vals[s];
        const int rr_ = f_ >> 9, q_ = j_ & 3;
        if (rr_ == 0) {
          if (q_ == 0) v0.x = vv_; else if (q_ == 1) v0.y = vv_;
          else if (q_ == 2) v0.z = vv_; else v0.w = vv_;
        } else {
          if (q_ == 0) v1.x = vv_; else if (q_ == 1) v1.y = vv_;
          else if (q_ == 2) v1.z = vv_; else v1.w = vv_;
        }
      }
      f4v* drow = dst4 + (size_t)s * (NC2_ / 4);
      __builtin_nontemporal_store(v0, drow + tid);
      __builtin_nontemporal_store(v1, drow + tid + 512);
    }
  }
}

extern "C" void kernel_launch(void* const* d_in, const int* in_sizes, int n_in,
                              void* d_out, int out_size, void* d_ws, size_t ws_size,
                              hipStream_t stream) {
  const int* c2_seq = (const int*)d_in[1];
  const int* d_seq = (const int*)d_in[3];
  const int* r_seq = (const int*)d_in[4];
  const float* D_emb = (const float*)d_in[5];
  const float* v_d = (const float*)d_in[6];
  const float* v_c2 = (const float*)d_in[7];
  const float* R_emb = (const float*)d_in[8];
  const float* W_ih = (const float*)d_in[9];
  const float* W_hh = (const float*)d_in[10];
  const float* b_ih = (const float*)d_in[11];
  const float* b_hh = (const float*)d_in[12];
  const float* W1 = (const float*)d_in[13];
  const float* b1 = (const float*)d_in[14];
  const float* W2 = (const float*)d_in[15];
  const float* b2 = (const float*)d_in[16];
  const float* W3 = (const float*)d_in[17];
  const float* b3 = (const float*)d_in[18];
  const float* W4 = (const float*)d_in[19];
  const float* b4 = (const float*)d_in[20];

  float* out = (float*)d_out;
  float* out_alpha = out;                                  // [B,S]
  float* out_h = out + B_ * S_;                            // [B,S,DV]
  float* out_c2 = out + B_ * S_ + (size_t)B_ * S_ * DV_;   // [B,S,NC2]

  k1_main<<<dim3(2 * B_), dim3(512), 0, stream>>>(
      c2_seq, d_seq, r_seq, D_emb, v_d, v_c2, R_emb, W_ih, W_hh, b_ih, b_hh,
      W1, b1, W2, b2, W3, b3, W4, b4, out_alpha, out_h, out_c2);
}